// Round 7
// baseline (276.876 us; speedup 1.0000x reference)
//
#include <hip/hip_runtime.h>

#define NN   1024
#define TT   12
#define CC   64
#define DD   64
#define HH   2
#define KK   3
#define ETOT 17408           // E (16384) + N self loops
#define BT   48              // B*T
#define BTH  96              // B*T*H
#define HD   128             // H*D
#define NSL  24              // slices: (btg4 0..11) x (h 0..1)
#define CSR_CAP (KK * ETOT + 24 * NN)      // each (k,n) segment padded to x8

__device__ __forceinline__ float bf_lo(unsigned int u) {
    return __uint_as_float(u << 16);
}
__device__ __forceinline__ float bf_hi(unsigned int u) {
    return __uint_as_float(u & 0xFFFF0000u);
}
__device__ __forceinline__ unsigned short f2bf(float f) {
    unsigned int u = __float_as_uint(f);
    u += 0x7FFFu + ((u >> 16) & 1u);      // round-to-nearest-even
    return (unsigned short)(u >> 16);
}
__device__ __forceinline__ unsigned int pack2(float a, float b) {
    return (unsigned int)f2bf(a) | ((unsigned int)f2bf(b) << 16);
}

// ---------------- Pass 0: alc/arc = fc_w @ attn_{l,r}  [K,H,C] --------------
__global__ __launch_bounds__(64) void prep_alc(
    const float* __restrict__ fc_w, const float* __restrict__ attn_l,
    const float* __restrict__ attn_r, float* __restrict__ alc, float* __restrict__ arc)
{
    int kh = blockIdx.x;            // 0..5
    int k = kh >> 1, h = kh & 1;
    int c = threadIdx.x;            // 0..63
    float sl = 0.f, sr = 0.f;
    #pragma unroll
    for (int d = 0; d < 64; ++d) {
        float w = fc_w[k * CC * HD + c * HD + h * 64 + d];
        sl = fmaf(w, attn_l[k * HD + h * 64 + d], sl);
        sr = fmaf(w, attn_r[k * HD + h * 64 + d], sr);
    }
    alc[kh * 64 + c] = sl;
    arc[kh * 64 + c] = sr;
}

// ---------------- Pass A: feat = x @ fc_w (bf16, slice layout), el/er -------
// featp (uint2): [s=(btg4*2+h)][k][n][d] ; uint2 = 4 bt values (bt=btg4*4+0..3)
__global__ __launch_bounds__(128) void feat_kernel(
    const float* __restrict__ x,       // [B,N,T,C]
    const float* __restrict__ fc_w,    // [K,C,HD]
    const float* __restrict__ alc,     // [K,H,C]
    const float* __restrict__ arc,
    uint2* __restrict__ featp,
    float* __restrict__ el,
    float* __restrict__ er)
{
    int k = blockIdx.x / NN;
    int n = blockIdx.x % NN;
    int e = threadIdx.x;          // 0..127
    int h = e >> 6, d = e & 63;

    __shared__ float x_lds[BT * CC];   // 12 KB

    float wreg[CC];
    #pragma unroll
    for (int c = 0; c < CC; ++c) wreg[c] = fc_w[k * CC * HD + c * HD + e];

    for (int i = e; i < BT * CC; i += 128) {
        int bt = i >> 6, c = i & 63;
        int b = bt / TT, t = bt - b * TT;
        x_lds[i] = x[(((size_t)b * NN + n) * TT + t) * CC + c];
    }
    __syncthreads();

    if (e < BTH) {
        int hh = e / BT, bt = e - hh * BT;
        const float* alp = &alc[(k * HH + hh) * CC];
        const float* arp = &arc[(k * HH + hh) * CC];
        const float* xr = &x_lds[bt * CC];
        float sl = 0.f, sr = 0.f;
        #pragma unroll
        for (int cc = 0; cc < CC; ++cc) {
            int c = (cc + bt) & 63;           // stagger: avoid LDS conflicts
            float xv = xr[c];
            sl = fmaf(xv, alp[c], sl);
            sr = fmaf(xv, arp[c], sr);
        }
        el[(k * NN + n) * BTH + e] = sl;
        er[(k * NN + n) * BTH + e] = sr;
    }

    for (int btg4 = 0; btg4 < 12; ++btg4) {
        float f4[4];
        #pragma unroll
        for (int i = 0; i < 4; ++i) {
            int bt = btg4 * 4 + i;
            const float* xr = &x_lds[bt * CC];
            float f = 0.f;
            #pragma unroll
            for (int c4 = 0; c4 < CC / 4; ++c4) {
                float4 xv = *(const float4*)&xr[c4 * 4];
                f = fmaf(xv.x, wreg[c4 * 4 + 0], f);
                f = fmaf(xv.y, wreg[c4 * 4 + 1], f);
                f = fmaf(xv.z, wreg[c4 * 4 + 2], f);
                f = fmaf(xv.w, wreg[c4 * 4 + 3], f);
            }
            f4[i] = f;
        }
        uint2 pk;
        pk.x = pack2(f4[0], f4[1]);
        pk.y = pack2(f4[2], f4[3]);
        int s = btg4 * 2 + h;
        featp[((size_t)s * (KK * NN) + k * NN + n) * 64 + d] = pk;
    }
}

// ---------------- CSR build (per-(k,n) segments, padded to 8) ---------------
__global__ void count_kernel(const int* __restrict__ dst_idx, int* __restrict__ counts)
{
    int tid = blockIdx.x * blockDim.x + threadIdx.x;
    if (tid < KK * ETOT) {
        int k = tid / ETOT;
        atomicAdd(&counts[k * NN + dst_idx[tid]], 1);
    }
}

__global__ __launch_bounds__(1024) void scan_kernel(
    const int* __restrict__ counts,
    int4* __restrict__ segs,         // [NN]: {s0, s1, s2, end}
    int* __restrict__ cursor,        // [K*NN]
    int* __restrict__ csr_comb)      // pad entries filled here
{
    int n = threadIdx.x;
    int c0 = counts[n], c1 = counts[NN + n], c2 = counts[2 * NN + n];
    int p0 = (c0 + 7) & ~7, p1 = (c1 + 7) & ~7, p2 = (c2 + 7) & ~7;
    int tot = p0 + p1 + p2;
    __shared__ int buf[NN];
    buf[n] = tot;
    __syncthreads();
    for (int off = 1; off < NN; off <<= 1) {
        int v = (n >= off) ? buf[n - off] : 0;
        __syncthreads();
        buf[n] += v;
        __syncthreads();
    }
    int excl = buf[n] - tot;
    int4 sg;
    sg.x = excl; sg.y = excl + p0; sg.z = excl + p0 + p1; sg.w = excl + tot;
    segs[n] = sg;
    cursor[n] = sg.x;
    cursor[NN + n] = sg.y;
    cursor[2 * NN + n] = sg.z;
    for (int j = sg.x + c0; j < sg.y; ++j) csr_comb[j] = n;            // k=0 pad
    for (int j = sg.y + c1; j < sg.z; ++j) csr_comb[j] = NN + n;       // k=1 pad
    for (int j = sg.z + c2; j < sg.w; ++j) csr_comb[j] = 2 * NN + n;   // k=2 pad
}

__global__ void scatter_kernel(const int* __restrict__ src_idx,
                               const int* __restrict__ dst_idx,
                               int* __restrict__ cursor, int* __restrict__ csr_comb)
{
    int tid = blockIdx.x * blockDim.x + threadIdx.x;
    if (tid < KK * ETOT) {
        int k = tid / ETOT;
        int pos = atomicAdd(&cursor[k * NN + dst_idx[tid]], 1);
        csr_comb[pos] = k * NN + src_idx[tid];
    }
}

// ---------------- Pass C: softmax, single pass; pads get alpha=0 ------------
__global__ __launch_bounds__(96) void attn_kernel(
    const float* __restrict__ el, const float* __restrict__ er,
    const int4* __restrict__ segs, const int* __restrict__ counts,
    const int* __restrict__ csr_comb,
    float* __restrict__ alpha, float* __restrict__ inv_denom)
{
    int k = blockIdx.x / NN, n = blockIdx.x % NN;
    int bth = threadIdx.x;          // 0..95
    int4 sg = segs[n];
    int base = (k == 0) ? sg.x : (k == 1) ? sg.y : sg.z;
    int pend = (k == 0) ? sg.y : (k == 1) ? sg.z : sg.w;
    int len  = counts[k * NN + n];
    const int* csp = csr_comb + base;
    float erv = er[(k * NN + n) * BTH + bth];

    float s = 0.f;
    int j = 0;
    for (; j + 4 <= len; j += 4) {
        int sa = csp[j], sb = csp[j + 1], sc = csp[j + 2], sd = csp[j + 3];
        float ea = el[(size_t)sa * BTH + bth] + erv;
        float eb = el[(size_t)sb * BTH + bth] + erv;
        float ec = el[(size_t)sc * BTH + bth] + erv;
        float ed = el[(size_t)sd * BTH + bth] + erv;
        ea = ea > 0.f ? ea : ea * 0.2f;  eb = eb > 0.f ? eb : eb * 0.2f;
        ec = ec > 0.f ? ec : ec * 0.2f;  ed = ed > 0.f ? ed : ed * 0.2f;
        float aa = __expf(ea), ab = __expf(eb), ac = __expf(ec), ad = __expf(ed);
        alpha[(size_t)(base + j + 0) * BTH + bth] = aa;
        alpha[(size_t)(base + j + 1) * BTH + bth] = ab;
        alpha[(size_t)(base + j + 2) * BTH + bth] = ac;
        alpha[(size_t)(base + j + 3) * BTH + bth] = ad;
        s += (aa + ab) + (ac + ad);
    }
    for (; j < len; ++j) {
        int src = csp[j];
        float ev = el[(size_t)src * BTH + bth] + erv;
        ev = ev > 0.f ? ev : ev * 0.2f;
        float a = __expf(ev);
        alpha[(size_t)(base + j) * BTH + bth] = a;
        s += a;
    }
    for (int jj = base + len; jj < pend; ++jj)       // zero pad slots
        alpha[(size_t)jj * BTH + bth] = 0.f;
    inv_denom[(k * NN + n) * BTH + bth] = 1.0f / s;
}

// ---------------- Pass D: aggregate, slice-pinned to XCDs -------------------
// grid: bid = xcd + 8*(sl*256 + g);  slice s = xcd + 8*sl  (s = btg4*2 + h)
// block: 256 thr = 4 waves; wave w handles n = g*4 + w for slice s.
#define EDGE_FMA4(F, J) {                                      \
    const float* ap = alp + (size_t)(J) * BTH;                 \
    float4 A = *(const float4*)ap;                             \
    r[0] = fmaf(A.x, bf_lo((F).x), r[0]);                      \
    r[1] = fmaf(A.y, bf_hi((F).x), r[1]);                      \
    r[2] = fmaf(A.z, bf_lo((F).y), r[2]);                      \
    r[3] = fmaf(A.w, bf_hi((F).y), r[3]); }

__global__ __launch_bounds__(256) void agg_kernel(
    const uint2* __restrict__ featp,
    const float* __restrict__ alpha,
    const float* __restrict__ inv_denom,
    const int4* __restrict__ segs, const int* __restrict__ csr_comb,
    const float* __restrict__ gat_bias, const float* __restrict__ weight,
    float* __restrict__ gat)           // [n][bt][HD] f32
{
    int xcd = blockIdx.x & 7;
    int jj  = blockIdx.x >> 3;
    int sl  = jj >> 8;                 // 0..2
    int g   = jj & 255;
    int s   = xcd + 8 * sl;            // 0..23
    int w   = threadIdx.x >> 6;        // 0..3
    int d   = threadIdx.x & 63;
    int n   = g * 4 + w;
    int btg4 = s >> 1, h = s & 1;
    int e = h * 64 + d;

    int4 sg = segs[n];
    const float* alp = alpha + h * BT + btg4 * 4;
    const uint2* fb = featp + (size_t)s * (KK * NN) * 64 + d;

    float acc[4] = {0.f, 0.f, 0.f, 0.f};

    #pragma unroll
    for (int k = 0; k < KK; ++k) {
        int jb = (k == 0) ? sg.x : (k == 1) ? sg.y : sg.z;
        int je = (k == 0) ? sg.y : (k == 1) ? sg.z : sg.w;

        float r[4] = {0.f, 0.f, 0.f, 0.f};

        for (int j0 = jb; j0 < je; j0 += 8) {
            int4 ia = *(const int4*)&csr_comb[j0];
            int4 ib = *(const int4*)&csr_comb[j0 + 4];
            uint2 f0 = fb[(size_t)ia.x * 64];
            uint2 f1 = fb[(size_t)ia.y * 64];
            uint2 f2 = fb[(size_t)ia.z * 64];
            uint2 f3 = fb[(size_t)ia.w * 64];
            EDGE_FMA4(f0, j0 + 0); EDGE_FMA4(f1, j0 + 1);
            EDGE_FMA4(f2, j0 + 2); EDGE_FMA4(f3, j0 + 3);
            uint2 f4 = fb[(size_t)ib.x * 64];
            uint2 f5 = fb[(size_t)ib.y * 64];
            uint2 f6 = fb[(size_t)ib.z * 64];
            uint2 f7 = fb[(size_t)ib.w * 64];
            EDGE_FMA4(f4, j0 + 4); EDGE_FMA4(f5, j0 + 5);
            EDGE_FMA4(f6, j0 + 6); EDGE_FMA4(f7, j0 + 7);
        }

        float4 iv = *(const float4*)&inv_denom[((size_t)k * NN + n) * BTH + h * BT + btg4 * 4];
        float wk = weight[k];
        float bias = gat_bias[k * HD + e];
        acc[0] = fmaf(wk, fmaf(r[0], iv.x, bias), acc[0]);
        acc[1] = fmaf(wk, fmaf(r[1], iv.y, bias), acc[1]);
        acc[2] = fmaf(wk, fmaf(r[2], iv.z, bias), acc[2]);
        acc[3] = fmaf(wk, fmaf(r[3], iv.w, bias), acc[3]);
    }

    #pragma unroll
    for (int i = 0; i < 4; ++i) {
        int bt = btg4 * 4 + i;
        gat[((size_t)n * BT + bt) * HD + e] = acc[i];
    }
}
#undef EDGE_FMA4

// ---------------- Pass E: merge GEMV + leakyrelu + residual -----------------
__global__ __launch_bounds__(128) void merge_kernel(
    const float* __restrict__ gat,
    const float* __restrict__ merge_w, const float* __restrict__ merge_b,
    const float* __restrict__ x, float* __restrict__ out)
{
    int m = blockIdx.x >> 10;        // 0..5 (8-bt group)
    int n = blockIdx.x & 1023;
    int e = threadIdx.x;             // 0..127

    __shared__ float rows[8][HD];    // 4 KB
    #pragma unroll
    for (int i = 0; i < 8; ++i)
        rows[i][e] = gat[((size_t)n * BT + m * 8 + i) * HD + e];
    __syncthreads();

    #pragma unroll
    for (int pass = 0; pass < 4; ++pass) {
        int oi = pass * 128 + e;     // 512 outputs: 8 rows x 64 cols
        int rr = oi >> 6, dd = oi & 63;
        float mg = merge_b[dd];
        #pragma unroll
        for (int q = 0; q < HD; ++q) mg = fmaf(rows[rr][q], merge_w[q * DD + dd], mg);
        mg = mg > 0.f ? mg : mg * 0.01f;
        int bt = m * 8 + rr;
        int b = bt / TT, t = bt - b * TT;
        size_t oidx = (((size_t)b * NN + n) * TT + t) * DD + dd;
        out[oidx] = mg + x[oidx];
    }
}

extern "C" void kernel_launch(void* const* d_in, const int* in_sizes, int n_in,
                              void* d_out, int out_size, void* d_ws, size_t ws_size,
                              hipStream_t stream)
{
    const float* x        = (const float*)d_in[0];
    const float* fc_w     = (const float*)d_in[1];
    const float* attn_l   = (const float*)d_in[2];
    const float* attn_r   = (const float*)d_in[3];
    const float* gat_bias = (const float*)d_in[4];
    const float* weight   = (const float*)d_in[5];
    const float* merge_w  = (const float*)d_in[6];
    const float* merge_b  = (const float*)d_in[7];
    const int*   src_idx  = (const int*)d_in[8];
    const int*   dst_idx  = (const int*)d_in[9];
    float*       out      = (float*)d_out;

    char* p = (char*)d_ws;
    auto carve = [&](size_t bytes) { char* r = p; p += (bytes + 15) & ~size_t(15); return r; };
    uint2* featp     = (uint2*)carve(sizeof(unsigned short) * (size_t)KK * NN * BT * HD); // 37.7 MB
    float* gat       = (float*)carve(sizeof(float) * (size_t)NN * BT * HD);               // 25.2 MB
    float* el        = (float*)carve(sizeof(float) * KK * NN * BTH);
    float* er        = (float*)carve(sizeof(float) * KK * NN * BTH);
    float* alpha     = (float*)carve(sizeof(float) * (size_t)CSR_CAP * BTH);              // ~28 MB
    float* inv_denom = (float*)carve(sizeof(float) * KK * NN * BTH);
    float* alc       = (float*)carve(sizeof(float) * KK * HH * CC);
    float* arc       = (float*)carve(sizeof(float) * KK * HH * CC);
    int*   counts    = (int*)carve(sizeof(int) * KK * NN);
    int*   cursor    = (int*)carve(sizeof(int) * KK * NN);
    int4*  segs      = (int4*)carve(sizeof(int4) * NN);
    int*   csr_comb  = (int*)carve(sizeof(int) * (CSR_CAP + 16));

    hipMemsetAsync(counts, 0, sizeof(int) * KK * NN, stream);

    prep_alc<<<KK * HH, 64, 0, stream>>>(fc_w, attn_l, attn_r, alc, arc);

    feat_kernel<<<KK * NN, 128, 0, stream>>>(x, fc_w, alc, arc, featp, el, er);

    int edgeBlocks = (KK * ETOT + 255) / 256;
    count_kernel<<<edgeBlocks, 256, 0, stream>>>(dst_idx, counts);
    scan_kernel<<<1, 1024, 0, stream>>>(counts, segs, cursor, csr_comb);
    scatter_kernel<<<edgeBlocks, 256, 0, stream>>>(src_idx, dst_idx, cursor, csr_comb);

    attn_kernel<<<KK * NN, 96, 0, stream>>>(el, er, segs, counts, csr_comb, alpha, inv_denom);

    agg_kernel<<<NSL * 256, 256, 0, stream>>>(
        featp, alpha, inv_denom, segs, csr_comb, gat_bias, weight, gat);

    merge_kernel<<<NN * 6, 128, 0, stream>>>(gat, merge_w, merge_b, x, out);
}

// Round 8
// 238.431 us; speedup vs baseline: 1.1612x; 1.1612x over previous
//
#include <hip/hip_runtime.h>

#define NN   1024
#define TT   12
#define CC   64
#define DD   64
#define HH   2
#define KK   3
#define ETOT 17408           // E (16384) + N self loops
#define BT   48              // B*T
#define BTH  96              // B*T*H
#define HD   128             // H*D
#define NODES (KK * NN + 1)  // +1 sentinel pad node (feat=0, el=-inf)
#define PADN  (KK * NN)
#define CSR_CAP (KK * ETOT + 12 * NN)   // segments padded to x4
#define LOG2E 1.44269504f

__device__ __forceinline__ float bf_lo(unsigned int u) {
    return __uint_as_float(u << 16);
}
__device__ __forceinline__ float bf_hi(unsigned int u) {
    return __uint_as_float(u & 0xFFFF0000u);
}
__device__ __forceinline__ unsigned short f2bf(float f) {
    unsigned int u = __float_as_uint(f);
    u += 0x7FFFu + ((u >> 16) & 1u);      // round-to-nearest-even
    return (unsigned short)(u >> 16);
}
__device__ __forceinline__ unsigned int pack2(float a, float b) {
    return (unsigned int)f2bf(a) | ((unsigned int)f2bf(b) << 16);
}
__device__ __forceinline__ float rlf(float v, int lane) {
    return __int_as_float(__builtin_amdgcn_readlane(__float_as_int(v), lane));
}

// ---------------- Pass A: feat = x @ fc_w (bf16, slice layout), el/er -------
// featp (uint2): [s=(btg4*2+h)][node=k*NN+n][d]  (uint2 = bt 0..3 of btg4, bf16)
// elp   (float): [s][node][4]  = log2e * el  for (bt=btg4*4+i, h)
// er    (float): [node][h*BT+bt] = log2e * er
__global__ __launch_bounds__(128) void feat_kernel(
    const float* __restrict__ x,       // [B,N,T,C]
    const float* __restrict__ fc_w,    // [K,C,HD]
    const float* __restrict__ attn_l,  // [K,H,D]
    const float* __restrict__ attn_r,
    uint2* __restrict__ featp,
    float* __restrict__ elp,
    float* __restrict__ er)
{
    int k = blockIdx.x / NN;
    int n = blockIdx.x % NN;
    int e = threadIdx.x;          // 0..127
    int h = e >> 6, d = e & 63;

    float wreg[CC];
    #pragma unroll
    for (int c = 0; c < CC; ++c) wreg[c] = fc_w[k * CC * HD + c * HD + e];

    float al = attn_l[k * HD + e] * LOG2E;
    float ar = attn_r[k * HD + e] * LOG2E;
    float el_keep = 0.f, er_keep = 0.f;

    for (int btg4 = 0; btg4 < 12; ++btg4) {
        float fh[4];
        #pragma unroll
        for (int i = 0; i < 4; ++i) {
            int bt = btg4 * 4 + i;
            int b = bt / TT, t = bt - b * TT;
            const float* xr = &x[(((size_t)b * NN + n) * TT + t) * CC];
            float f = 0.f;
            #pragma unroll
            for (int c4 = 0; c4 < CC / 4; ++c4) {
                float4 xv = *(const float4*)&xr[c4 * 4];   // uniform -> s_load
                f = fmaf(xv.x, wreg[c4 * 4 + 0], f);
                f = fmaf(xv.y, wreg[c4 * 4 + 1], f);
                f = fmaf(xv.z, wreg[c4 * 4 + 2], f);
                f = fmaf(xv.w, wreg[c4 * 4 + 3], f);
            }
            fh[i] = f;
            // el/er for this (bt, h): reduce f*al over the wave (64 d-lanes)
            float pl = f * al, pr = f * ar;
            #pragma unroll
            for (int off = 1; off < 64; off <<= 1) {
                pl += __shfl_xor(pl, off, 64);
                pr += __shfl_xor(pr, off, 64);
            }
            if (d == bt) { el_keep = pl; er_keep = pr; }
        }
        uint2 pk;
        pk.x = pack2(fh[0], fh[1]);
        pk.y = pack2(fh[2], fh[3]);
        int s = btg4 * 2 + h;
        featp[((size_t)s * NODES + k * NN + n) * 64 + d] = pk;
    }

    if (d < BT) {
        int s = (d >> 2) * 2 + h;                 // bt = d
        elp[((size_t)s * NODES + k * NN + n) * 4 + (d & 3)] = el_keep;
        er[((size_t)(k * NN + n)) * BTH + h * BT + d] = er_keep;
    }
}

// ---------------- pad-node init ---------------------------------------------
__global__ void init_pad_kernel(uint2* __restrict__ featp, float* __restrict__ elp)
{
    int t = blockIdx.x * 256 + threadIdx.x;
    if (t < 24 * 64) {
        int s = t >> 6, dd = t & 63;
        featp[((size_t)s * NODES + PADN) * 64 + dd] = make_uint2(0u, 0u);
    }
    if (t < 24 * 4) {
        int s = t >> 2, i = t & 3;
        elp[((size_t)s * NODES + PADN) * 4 + i] = -1e30f;   // alpha = 0 exactly
    }
}

// ---------------- CSR build (per-(k,n) segments, padded to 4) ---------------
__global__ void count_kernel(const int* __restrict__ dst_idx, int* __restrict__ counts)
{
    int tid = blockIdx.x * blockDim.x + threadIdx.x;
    if (tid < KK * ETOT) {
        int k = tid / ETOT;
        atomicAdd(&counts[k * NN + dst_idx[tid]], 1);
    }
}

__global__ __launch_bounds__(1024) void scan_kernel(
    const int* __restrict__ counts,
    int4* __restrict__ segs,         // [NN]: {s0, s1, s2, end}
    int* __restrict__ cursor,        // [K*NN]
    int* __restrict__ csr_comb)      // pad entries -> PADN
{
    int n = threadIdx.x;
    int c0 = counts[n], c1 = counts[NN + n], c2 = counts[2 * NN + n];
    int p0 = (c0 + 3) & ~3, p1 = (c1 + 3) & ~3, p2 = (c2 + 3) & ~3;
    int tot = p0 + p1 + p2;
    __shared__ int buf[NN];
    buf[n] = tot;
    __syncthreads();
    for (int off = 1; off < NN; off <<= 1) {
        int v = (n >= off) ? buf[n - off] : 0;
        __syncthreads();
        buf[n] += v;
        __syncthreads();
    }
    int excl = buf[n] - tot;
    int4 sg;
    sg.x = excl; sg.y = excl + p0; sg.z = excl + p0 + p1; sg.w = excl + tot;
    segs[n] = sg;
    cursor[n] = sg.x;
    cursor[NN + n] = sg.y;
    cursor[2 * NN + n] = sg.z;
    for (int j = sg.x + c0; j < sg.y; ++j) csr_comb[j] = PADN;
    for (int j = sg.y + c1; j < sg.z; ++j) csr_comb[j] = PADN;
    for (int j = sg.z + c2; j < sg.w; ++j) csr_comb[j] = PADN;
}

__global__ void scatter_kernel(const int* __restrict__ src_idx,
                               const int* __restrict__ dst_idx,
                               int* __restrict__ cursor, int* __restrict__ csr_comb)
{
    int tid = blockIdx.x * blockDim.x + threadIdx.x;
    if (tid < KK * ETOT) {
        int k = tid / ETOT;
        int pos = atomicAdd(&cursor[k * NN + dst_idx[tid]], 1);
        csr_comb[pos] = k * NN + src_idx[tid];
    }
}

// ---------------- Pass D: fused softmax + aggregate, slice-pinned to XCDs ---
// grid 6144: j=(bid>>3)+768*(bid&7) -> XCD x owns jobs [768x,768x+768) = 3 slices
// block: 256 thr = 4 waves; wave w handles n = g*4 + w for slice s.
__global__ __launch_bounds__(256) void agg_kernel(
    const uint2* __restrict__ featp,
    const float* __restrict__ elp,
    const float* __restrict__ er,
    const int4* __restrict__ segs, const int* __restrict__ csr_comb,
    const float* __restrict__ gat_bias, const float* __restrict__ weight,
    float* __restrict__ gat)           // [n][bt][HD] f32
{
    int j = ((int)blockIdx.x >> 3) + 768 * ((int)blockIdx.x & 7);
    int s = j >> 8;                    // 0..23
    int g = j & 255;
    int w = threadIdx.x >> 6;          // 0..3
    int d = threadIdx.x & 63;          // lane
    int n = g * 4 + w;
    int btg4 = s >> 1, h = s & 1;
    int e = h * 64 + d;

    const uint2* fb = featp + (size_t)s * NODES * 64 + d;
    const float* ep = elp + (size_t)s * NODES * 4;
    int4 sg = segs[n];

    float acc0 = 0.f, acc1 = 0.f, acc2 = 0.f, acc3 = 0.f;

    #pragma unroll
    for (int k = 0; k < KK; ++k) {
        int jb = (k == 0) ? sg.x : (k == 1) ? sg.y : sg.z;
        int je = (k == 0) ? sg.y : (k == 1) ? sg.z : sg.w;
        float4 er4 = *(const float4*)&er[((size_t)(k * NN + n)) * BTH + h * BT + btg4 * 4];

        float ss0 = 0.f, ss1 = 0.f, ss2 = 0.f, ss3 = 0.f;
        float r0 = 0.f, r1 = 0.f, r2 = 0.f, r3 = 0.f;

        for (int j0 = jb; j0 < je; j0 += 64) {
            // ---- batch phase: lane L computes alphas for edge j0+L ----
            int lj = j0 + d;
            int idx = PADN;
            if (lj < je) idx = csr_comb[lj];
            float4 ev = *(const float4*)&ep[idx * 4];
            float t0 = ev.x + er4.x, t1 = ev.y + er4.y;
            float t2 = ev.z + er4.z, t3 = ev.w + er4.w;
            t0 = fmaxf(t0, t0 * 0.2f); t1 = fmaxf(t1, t1 * 0.2f);
            t2 = fmaxf(t2, t2 * 0.2f); t3 = fmaxf(t3, t3 * 0.2f);
            float a0 = __builtin_amdgcn_exp2f(t0);
            float a1 = __builtin_amdgcn_exp2f(t1);
            float a2 = __builtin_amdgcn_exp2f(t2);
            float a3 = __builtin_amdgcn_exp2f(t3);
            ss0 += a0; ss1 += a1; ss2 += a2; ss3 += a3;

            // ---- FMA phase: broadcast (src, alpha) from lane u ----
            int mm = je - j0; if (mm > 64) mm = 64;    // multiple of 4
            for (int u = 0; u < mm; u += 4) {
                int i0 = __builtin_amdgcn_readlane(idx, u + 0);
                int i1 = __builtin_amdgcn_readlane(idx, u + 1);
                int i2 = __builtin_amdgcn_readlane(idx, u + 2);
                int i3 = __builtin_amdgcn_readlane(idx, u + 3);
                uint2 f0 = fb[(size_t)i0 * 64];
                uint2 f1 = fb[(size_t)i1 * 64];
                uint2 f2 = fb[(size_t)i2 * 64];
                uint2 f3 = fb[(size_t)i3 * 64];

                float p0 = rlf(a0, u + 0), p1 = rlf(a1, u + 0),
                      p2 = rlf(a2, u + 0), p3 = rlf(a3, u + 0);
                r0 = fmaf(p0, bf_lo(f0.x), r0); r1 = fmaf(p1, bf_hi(f0.x), r1);
                r2 = fmaf(p2, bf_lo(f0.y), r2); r3 = fmaf(p3, bf_hi(f0.y), r3);

                p0 = rlf(a0, u + 1); p1 = rlf(a1, u + 1);
                p2 = rlf(a2, u + 1); p3 = rlf(a3, u + 1);
                r0 = fmaf(p0, bf_lo(f1.x), r0); r1 = fmaf(p1, bf_hi(f1.x), r1);
                r2 = fmaf(p2, bf_lo(f1.y), r2); r3 = fmaf(p3, bf_hi(f1.y), r3);

                p0 = rlf(a0, u + 2); p1 = rlf(a1, u + 2);
                p2 = rlf(a2, u + 2); p3 = rlf(a3, u + 2);
                r0 = fmaf(p0, bf_lo(f2.x), r0); r1 = fmaf(p1, bf_hi(f2.x), r1);
                r2 = fmaf(p2, bf_lo(f2.y), r2); r3 = fmaf(p3, bf_hi(f2.y), r3);

                p0 = rlf(a0, u + 3); p1 = rlf(a1, u + 3);
                p2 = rlf(a2, u + 3); p3 = rlf(a3, u + 3);
                r0 = fmaf(p0, bf_lo(f3.x), r0); r1 = fmaf(p1, bf_hi(f3.x), r1);
                r2 = fmaf(p2, bf_lo(f3.y), r2); r3 = fmaf(p3, bf_hi(f3.y), r3);
            }
        }

        // denominators: reduce per-lane partial sums across the wave
        #pragma unroll
        for (int off = 1; off < 64; off <<= 1) {
            ss0 += __shfl_xor(ss0, off, 64);
            ss1 += __shfl_xor(ss1, off, 64);
            ss2 += __shfl_xor(ss2, off, 64);
            ss3 += __shfl_xor(ss3, off, 64);
        }
        float wk = weight[k];
        acc0 = fmaf(r0, wk * __builtin_amdgcn_rcpf(ss0), acc0);
        acc1 = fmaf(r1, wk * __builtin_amdgcn_rcpf(ss1), acc1);
        acc2 = fmaf(r2, wk * __builtin_amdgcn_rcpf(ss2), acc2);
        acc3 = fmaf(r3, wk * __builtin_amdgcn_rcpf(ss3), acc3);
    }

    float wb = weight[0] * gat_bias[e] + weight[1] * gat_bias[HD + e]
             + weight[2] * gat_bias[2 * HD + e];
    acc0 += wb; acc1 += wb; acc2 += wb; acc3 += wb;

    gat[((size_t)n * BT + btg4 * 4 + 0) * HD + e] = acc0;
    gat[((size_t)n * BT + btg4 * 4 + 1) * HD + e] = acc1;
    gat[((size_t)n * BT + btg4 * 4 + 2) * HD + e] = acc2;
    gat[((size_t)n * BT + btg4 * 4 + 3) * HD + e] = acc3;
}

// ---------------- Pass E: merge GEMV + leakyrelu + residual -----------------
__global__ __launch_bounds__(128) void merge_kernel(
    const float* __restrict__ gat,
    const float* __restrict__ merge_w, const float* __restrict__ merge_b,
    const float* __restrict__ x, float* __restrict__ out)
{
    int m = blockIdx.x >> 10;        // 0..5 (8-bt group)
    int n = blockIdx.x & 1023;
    int e = threadIdx.x;             // 0..127

    __shared__ float rows[8][HD];    // 4 KB
    #pragma unroll
    for (int i = 0; i < 8; ++i)
        rows[i][e] = gat[((size_t)n * BT + m * 8 + i) * HD + e];
    __syncthreads();

    #pragma unroll
    for (int pass = 0; pass < 4; ++pass) {
        int oi = pass * 128 + e;     // 512 outputs: 8 rows x 64 cols
        int rr = oi >> 6, dd = oi & 63;
        float mg = merge_b[dd];
        #pragma unroll
        for (int q = 0; q < HD; ++q) mg = fmaf(rows[rr][q], merge_w[q * DD + dd], mg);
        mg = mg > 0.f ? mg : mg * 0.01f;
        int bt = m * 8 + rr;
        int b = bt / TT, t = bt - b * TT;
        size_t oidx = (((size_t)b * NN + n) * TT + t) * DD + dd;
        out[oidx] = mg + x[oidx];
    }
}

extern "C" void kernel_launch(void* const* d_in, const int* in_sizes, int n_in,
                              void* d_out, int out_size, void* d_ws, size_t ws_size,
                              hipStream_t stream)
{
    const float* x        = (const float*)d_in[0];
    const float* fc_w     = (const float*)d_in[1];
    const float* attn_l   = (const float*)d_in[2];
    const float* attn_r   = (const float*)d_in[3];
    const float* gat_bias = (const float*)d_in[4];
    const float* weight   = (const float*)d_in[5];
    const float* merge_w  = (const float*)d_in[6];
    const float* merge_b  = (const float*)d_in[7];
    const int*   src_idx  = (const int*)d_in[8];
    const int*   dst_idx  = (const int*)d_in[9];
    float*       out      = (float*)d_out;

    char* p = (char*)d_ws;
    auto carve = [&](size_t bytes) { char* r = p; p += (bytes + 15) & ~size_t(15); return r; };
    uint2* featp   = (uint2*)carve(sizeof(uint2) * (size_t)24 * NODES * 64);   // 37.8 MB
    float* elp     = (float*)carve(sizeof(float) * (size_t)24 * NODES * 4);    // 1.18 MB
    float* er      = (float*)carve(sizeof(float) * (size_t)KK * NN * BTH);     // 1.18 MB
    float* gat     = (float*)carve(sizeof(float) * (size_t)NN * BT * HD);      // 25.2 MB
    int*   counts  = (int*)carve(sizeof(int) * KK * NN);
    int*   cursor  = (int*)carve(sizeof(int) * KK * NN);
    int4*  segs    = (int4*)carve(sizeof(int4) * NN);
    int*   csr_comb= (int*)carve(sizeof(int) * (CSR_CAP + 80));

    hipMemsetAsync(counts, 0, sizeof(int) * KK * NN, stream);

    init_pad_kernel<<<6, 256, 0, stream>>>(featp, elp);

    feat_kernel<<<KK * NN, 128, 0, stream>>>(x, fc_w, attn_l, attn_r, featp, elp, er);

    int edgeBlocks = (KK * ETOT + 255) / 256;
    count_kernel<<<edgeBlocks, 256, 0, stream>>>(dst_idx, counts);
    scan_kernel<<<1, 1024, 0, stream>>>(counts, segs, cursor, csr_comb);
    scatter_kernel<<<edgeBlocks, 256, 0, stream>>>(src_idx, dst_idx, cursor, csr_comb);

    agg_kernel<<<24 * 256, 256, 0, stream>>>(
        featp, elp, er, segs, csr_comb, gat_bias, weight, gat);

    merge_kernel<<<NN * 6, 128, 0, stream>>>(gat, merge_w, merge_b, x, out);
}

// Round 9
// 223.861 us; speedup vs baseline: 1.2368x; 1.0651x over previous
//
#include <hip/hip_runtime.h>

#define NN   1024
#define TT   12
#define CC   64
#define DD   64
#define HH   2
#define KK   3
#define ETOT 17408           // E (16384) + N self loops
#define BT   48              // B*T
#define BTH  96              // B*T*H
#define HD   128             // H*D
#define NODES (KK * NN + 1)  // +1 sentinel pad node (feat=0, el=-inf)
#define PADN  (KK * NN)
#define CSR_CAP (KK * ETOT + 12 * NN)   // segments padded to x4
#define LOG2E 1.44269504f

__device__ __forceinline__ float bf_lo(unsigned int u) {
    return __uint_as_float(u << 16);
}
__device__ __forceinline__ float bf_hi(unsigned int u) {
    return __uint_as_float(u & 0xFFFF0000u);
}
__device__ __forceinline__ unsigned short f2bf(float f) {
    unsigned int u = __float_as_uint(f);
    u += 0x7FFFu + ((u >> 16) & 1u);      // round-to-nearest-even
    return (unsigned short)(u >> 16);
}
__device__ __forceinline__ unsigned int pack2(float a, float b) {
    return (unsigned int)f2bf(a) | ((unsigned int)f2bf(b) << 16);
}
__device__ __forceinline__ float rlf(float v, int lane) {
    return __int_as_float(__builtin_amdgcn_readlane(__float_as_int(v), lane));
}

// ---------------- Pass 0: alc/arc = log2e * (fc_w @ attn_{l,r})  [K,H,C] ----
__global__ __launch_bounds__(64) void prep_alc(
    const float* __restrict__ fc_w, const float* __restrict__ attn_l,
    const float* __restrict__ attn_r, float* __restrict__ alc, float* __restrict__ arc)
{
    int kh = blockIdx.x;            // 0..5
    int k = kh >> 1, h = kh & 1;
    int c = threadIdx.x;            // 0..63
    float sl = 0.f, sr = 0.f;
    #pragma unroll
    for (int d = 0; d < 64; ++d) {
        float w = fc_w[k * CC * HD + c * HD + h * 64 + d];
        sl = fmaf(w, attn_l[k * HD + h * 64 + d], sl);
        sr = fmaf(w, attn_r[k * HD + h * 64 + d], sr);
    }
    alc[kh * 64 + c] = sl * LOG2E;
    arc[kh * 64 + c] = sr * LOG2E;
}

// ---------------- Pass A: feat = x @ fc_w (bf16, slice layout), el/er -------
// featp (uint2): [s=(btg4*2+h)][node=k*NN+n][d]  (uint2 = bt 0..3 of btg4, bf16)
// elp   (float): [s][node][4]  = log2e * el
// er    (float): [node][h*BT+bt] = log2e * er
__global__ __launch_bounds__(128) void feat_kernel(
    const float* __restrict__ x,       // [B,N,T,C]
    const float* __restrict__ fc_w,    // [K,C,HD]
    const float* __restrict__ alc,     // [K,H,C] (log2e-scaled)
    const float* __restrict__ arc,
    uint2* __restrict__ featp,
    float* __restrict__ elp,
    float* __restrict__ er)
{
    int k = blockIdx.x / NN;
    int n = blockIdx.x % NN;
    int e = threadIdx.x;          // 0..127
    int h = e >> 6, d = e & 63;

    __shared__ float x_lds[BT * CC];   // 12 KB

    float wreg[CC];
    #pragma unroll
    for (int c = 0; c < CC; ++c) wreg[c] = fc_w[k * CC * HD + c * HD + e];

    for (int i = e; i < BT * CC; i += 128) {
        int bt = i >> 6, c = i & 63;
        int b = bt / TT, t = bt - b * TT;
        x_lds[i] = x[(((size_t)b * NN + n) * TT + t) * CC + c];
    }
    __syncthreads();

    // el/er via precomputed coefficient vectors (no shuffles)
    if (e < BTH) {
        int hh = e / BT, bt = e - hh * BT;
        const float* alp = &alc[(k * HH + hh) * CC];
        const float* arp = &arc[(k * HH + hh) * CC];
        const float* xr = &x_lds[bt * CC];
        float sl = 0.f, sr = 0.f;
        #pragma unroll
        for (int cc = 0; cc < CC; ++cc) {
            int c = (cc + bt) & 63;           // stagger: avoid LDS conflicts
            float xv = xr[c];
            sl = fmaf(xv, alp[c], sl);
            sr = fmaf(xv, arp[c], sr);
        }
        int s = (bt >> 2) * 2 + hh;
        elp[((size_t)s * NODES + k * NN + n) * 4 + (bt & 3)] = sl;
        er[((size_t)(k * NN + n)) * BTH + e] = sr;    // e = hh*BT+bt
    }

    for (int btg4 = 0; btg4 < 12; ++btg4) {
        float f4[4];
        #pragma unroll
        for (int i = 0; i < 4; ++i) {
            int bt = btg4 * 4 + i;
            const float* xr = &x_lds[bt * CC];
            float f = 0.f;
            #pragma unroll
            for (int c4 = 0; c4 < CC / 4; ++c4) {
                float4 xv = *(const float4*)&xr[c4 * 4];
                f = fmaf(xv.x, wreg[c4 * 4 + 0], f);
                f = fmaf(xv.y, wreg[c4 * 4 + 1], f);
                f = fmaf(xv.z, wreg[c4 * 4 + 2], f);
                f = fmaf(xv.w, wreg[c4 * 4 + 3], f);
            }
            f4[i] = f;
        }
        uint2 pk;
        pk.x = pack2(f4[0], f4[1]);
        pk.y = pack2(f4[2], f4[3]);
        int s = btg4 * 2 + h;
        featp[((size_t)s * NODES + k * NN + n) * 64 + d] = pk;
    }
}

// ---------------- pad-node init ---------------------------------------------
__global__ void init_pad_kernel(uint2* __restrict__ featp, float* __restrict__ elp)
{
    int t = blockIdx.x * 256 + threadIdx.x;
    if (t < 24 * 64) {
        int s = t >> 6, dd = t & 63;
        featp[((size_t)s * NODES + PADN) * 64 + dd] = make_uint2(0u, 0u);
    }
    if (t < 24 * 4) {
        int s = t >> 2, i = t & 3;
        elp[((size_t)s * NODES + PADN) * 4 + i] = -1e30f;   // alpha = 0 exactly
    }
}

// ---------------- CSR build (per-(k,n) segments, padded to 4) ---------------
__global__ void count_kernel(const int* __restrict__ dst_idx, int* __restrict__ counts)
{
    int tid = blockIdx.x * blockDim.x + threadIdx.x;
    if (tid < KK * ETOT) {
        int k = tid / ETOT;
        atomicAdd(&counts[k * NN + dst_idx[tid]], 1);
    }
}

__global__ __launch_bounds__(1024) void scan_kernel(
    const int* __restrict__ counts,
    int4* __restrict__ segs,         // [NN]: {s0, s1, s2, end}
    int* __restrict__ cursor,        // [K*NN]
    int* __restrict__ csr_comb)      // pad entries -> PADN
{
    int n = threadIdx.x;
    int c0 = counts[n], c1 = counts[NN + n], c2 = counts[2 * NN + n];
    int p0 = (c0 + 3) & ~3, p1 = (c1 + 3) & ~3, p2 = (c2 + 3) & ~3;
    int tot = p0 + p1 + p2;
    __shared__ int buf[NN];
    buf[n] = tot;
    __syncthreads();
    for (int off = 1; off < NN; off <<= 1) {
        int v = (n >= off) ? buf[n - off] : 0;
        __syncthreads();
        buf[n] += v;
        __syncthreads();
    }
    int excl = buf[n] - tot;
    int4 sg;
    sg.x = excl; sg.y = excl + p0; sg.z = excl + p0 + p1; sg.w = excl + tot;
    segs[n] = sg;
    cursor[n] = sg.x;
    cursor[NN + n] = sg.y;
    cursor[2 * NN + n] = sg.z;
    for (int j = sg.x + c0; j < sg.y; ++j) csr_comb[j] = PADN;
    for (int j = sg.y + c1; j < sg.z; ++j) csr_comb[j] = PADN;
    for (int j = sg.z + c2; j < sg.w; ++j) csr_comb[j] = PADN;
}

__global__ void scatter_kernel(const int* __restrict__ src_idx,
                               const int* __restrict__ dst_idx,
                               int* __restrict__ cursor, int* __restrict__ csr_comb)
{
    int tid = blockIdx.x * blockDim.x + threadIdx.x;
    if (tid < KK * ETOT) {
        int k = tid / ETOT;
        int pos = atomicAdd(&cursor[k * NN + dst_idx[tid]], 1);
        csr_comb[pos] = k * NN + src_idx[tid];
    }
}

// ---------------- Pass D: fused softmax + aggregate, slice-pinned to XCDs ---
// grid 6144: j=(bid>>3)+768*(bid&7) -> XCD x owns jobs [768x,768x+768) = 3 slices
// block: 256 thr = 4 waves; wave w handles n = g*4 + w for slice s.
__global__ __launch_bounds__(256) void agg_kernel(
    const uint2* __restrict__ featp,
    const float* __restrict__ elp,
    const float* __restrict__ er,
    const int4* __restrict__ segs, const int* __restrict__ csr_comb,
    const float* __restrict__ gat_bias, const float* __restrict__ weight,
    float* __restrict__ gat)           // [n][bt][HD] f32
{
    int j = ((int)blockIdx.x >> 3) + 768 * ((int)blockIdx.x & 7);
    int s = j >> 8;                    // 0..23
    int g = j & 255;
    int w = threadIdx.x >> 6;          // 0..3
    int d = threadIdx.x & 63;          // lane
    int n = g * 4 + w;
    int btg4 = s >> 1, h = s & 1;
    int e = h * 64 + d;

    const uint2* fb = featp + (size_t)s * NODES * 64 + d;
    const float* ep = elp + (size_t)s * NODES * 4;
    int4 sg = segs[n];

    float acc0 = 0.f, acc1 = 0.f, acc2 = 0.f, acc3 = 0.f;

    #pragma unroll
    for (int k = 0; k < KK; ++k) {
        int jb = (k == 0) ? sg.x : (k == 1) ? sg.y : sg.z;
        int je = (k == 0) ? sg.y : (k == 1) ? sg.z : sg.w;
        float4 er4 = *(const float4*)&er[((size_t)(k * NN + n)) * BTH + h * BT + btg4 * 4];

        float ss0 = 0.f, ss1 = 0.f, ss2 = 0.f, ss3 = 0.f;
        float r0 = 0.f, r1 = 0.f, r2 = 0.f, r3 = 0.f;

        for (int j0 = jb; j0 < je; j0 += 64) {
            // ---- batch phase: lane L computes alphas for edge j0+L ----
            int lj = j0 + d;
            int idx = PADN;
            if (lj < je) idx = csr_comb[lj];
            float4 ev = *(const float4*)&ep[idx * 4];
            float t0 = ev.x + er4.x, t1 = ev.y + er4.y;
            float t2 = ev.z + er4.z, t3 = ev.w + er4.w;
            t0 = fmaxf(t0, t0 * 0.2f); t1 = fmaxf(t1, t1 * 0.2f);
            t2 = fmaxf(t2, t2 * 0.2f); t3 = fmaxf(t3, t3 * 0.2f);
            float a0 = __builtin_amdgcn_exp2f(t0);
            float a1 = __builtin_amdgcn_exp2f(t1);
            float a2 = __builtin_amdgcn_exp2f(t2);
            float a3 = __builtin_amdgcn_exp2f(t3);
            ss0 += a0; ss1 += a1; ss2 += a2; ss3 += a3;

            // ---- FMA phase: broadcast (src, alpha) from lane u ----
            int mm = je - j0; if (mm > 64) mm = 64;    // multiple of 4
            for (int u = 0; u < mm; u += 4) {
                int i0 = __builtin_amdgcn_readlane(idx, u + 0);
                int i1 = __builtin_amdgcn_readlane(idx, u + 1);
                int i2 = __builtin_amdgcn_readlane(idx, u + 2);
                int i3 = __builtin_amdgcn_readlane(idx, u + 3);
                uint2 f0 = fb[(size_t)i0 * 64];
                uint2 f1 = fb[(size_t)i1 * 64];
                uint2 f2 = fb[(size_t)i2 * 64];
                uint2 f3 = fb[(size_t)i3 * 64];

                float p0 = rlf(a0, u + 0), p1 = rlf(a1, u + 0),
                      p2 = rlf(a2, u + 0), p3 = rlf(a3, u + 0);
                r0 = fmaf(p0, bf_lo(f0.x), r0); r1 = fmaf(p1, bf_hi(f0.x), r1);
                r2 = fmaf(p2, bf_lo(f0.y), r2); r3 = fmaf(p3, bf_hi(f0.y), r3);

                p0 = rlf(a0, u + 1); p1 = rlf(a1, u + 1);
                p2 = rlf(a2, u + 1); p3 = rlf(a3, u + 1);
                r0 = fmaf(p0, bf_lo(f1.x), r0); r1 = fmaf(p1, bf_hi(f1.x), r1);
                r2 = fmaf(p2, bf_lo(f1.y), r2); r3 = fmaf(p3, bf_hi(f1.y), r3);

                p0 = rlf(a0, u + 2); p1 = rlf(a1, u + 2);
                p2 = rlf(a2, u + 2); p3 = rlf(a3, u + 2);
                r0 = fmaf(p0, bf_lo(f2.x), r0); r1 = fmaf(p1, bf_hi(f2.x), r1);
                r2 = fmaf(p2, bf_lo(f2.y), r2); r3 = fmaf(p3, bf_hi(f2.y), r3);

                p0 = rlf(a0, u + 3); p1 = rlf(a1, u + 3);
                p2 = rlf(a2, u + 3); p3 = rlf(a3, u + 3);
                r0 = fmaf(p0, bf_lo(f3.x), r0); r1 = fmaf(p1, bf_hi(f3.x), r1);
                r2 = fmaf(p2, bf_lo(f3.y), r2); r3 = fmaf(p3, bf_hi(f3.y), r3);
            }
        }

        // denominators: reduce per-lane partial sums across the wave
        #pragma unroll
        for (int off = 1; off < 64; off <<= 1) {
            ss0 += __shfl_xor(ss0, off, 64);
            ss1 += __shfl_xor(ss1, off, 64);
            ss2 += __shfl_xor(ss2, off, 64);
            ss3 += __shfl_xor(ss3, off, 64);
        }
        float wk = weight[k];
        acc0 = fmaf(r0, wk * __builtin_amdgcn_rcpf(ss0), acc0);
        acc1 = fmaf(r1, wk * __builtin_amdgcn_rcpf(ss1), acc1);
        acc2 = fmaf(r2, wk * __builtin_amdgcn_rcpf(ss2), acc2);
        acc3 = fmaf(r3, wk * __builtin_amdgcn_rcpf(ss3), acc3);
    }

    float wb = weight[0] * gat_bias[e] + weight[1] * gat_bias[HD + e]
             + weight[2] * gat_bias[2 * HD + e];
    acc0 += wb; acc1 += wb; acc2 += wb; acc3 += wb;

    gat[((size_t)n * BT + btg4 * 4 + 0) * HD + e] = acc0;
    gat[((size_t)n * BT + btg4 * 4 + 1) * HD + e] = acc1;
    gat[((size_t)n * BT + btg4 * 4 + 2) * HD + e] = acc2;
    gat[((size_t)n * BT + btg4 * 4 + 3) * HD + e] = acc3;
}

// ---------------- Pass E: merge GEMV + leakyrelu + residual -----------------
__global__ __launch_bounds__(128) void merge_kernel(
    const float* __restrict__ gat,
    const float* __restrict__ merge_w, const float* __restrict__ merge_b,
    const float* __restrict__ x, float* __restrict__ out)
{
    int m = blockIdx.x >> 10;        // 0..5 (8-bt group)
    int n = blockIdx.x & 1023;
    int e = threadIdx.x;             // 0..127

    __shared__ float rows[8][HD];    // 4 KB
    #pragma unroll
    for (int i = 0; i < 8; ++i)
        rows[i][e] = gat[((size_t)n * BT + m * 8 + i) * HD + e];
    __syncthreads();

    #pragma unroll
    for (int pass = 0; pass < 4; ++pass) {
        int oi = pass * 128 + e;     // 512 outputs: 8 rows x 64 cols
        int rr = oi >> 6, dd = oi & 63;
        float mg = merge_b[dd];
        #pragma unroll
        for (int q = 0; q < HD; ++q) mg = fmaf(rows[rr][q], merge_w[q * DD + dd], mg);
        mg = mg > 0.f ? mg : mg * 0.01f;
        int bt = m * 8 + rr;
        int b = bt / TT, t = bt - b * TT;
        size_t oidx = (((size_t)b * NN + n) * TT + t) * DD + dd;
        out[oidx] = mg + x[oidx];
    }
}

extern "C" void kernel_launch(void* const* d_in, const int* in_sizes, int n_in,
                              void* d_out, int out_size, void* d_ws, size_t ws_size,
                              hipStream_t stream)
{
    const float* x        = (const float*)d_in[0];
    const float* fc_w     = (const float*)d_in[1];
    const float* attn_l   = (const float*)d_in[2];
    const float* attn_r   = (const float*)d_in[3];
    const float* gat_bias = (const float*)d_in[4];
    const float* weight   = (const float*)d_in[5];
    const float* merge_w  = (const float*)d_in[6];
    const float* merge_b  = (const float*)d_in[7];
    const int*   src_idx  = (const int*)d_in[8];
    const int*   dst_idx  = (const int*)d_in[9];
    float*       out      = (float*)d_out;

    char* p = (char*)d_ws;
    auto carve = [&](size_t bytes) { char* r = p; p += (bytes + 15) & ~size_t(15); return r; };
    uint2* featp   = (uint2*)carve(sizeof(uint2) * (size_t)24 * NODES * 64);   // 37.8 MB
    float* elp     = (float*)carve(sizeof(float) * (size_t)24 * NODES * 4);    // 1.18 MB
    float* er      = (float*)carve(sizeof(float) * (size_t)KK * NN * BTH);     // 1.18 MB
    float* gat     = (float*)carve(sizeof(float) * (size_t)NN * BT * HD);      // 25.2 MB
    float* alc     = (float*)carve(sizeof(float) * KK * HH * CC);
    float* arc     = (float*)carve(sizeof(float) * KK * HH * CC);
    int*   counts  = (int*)carve(sizeof(int) * KK * NN);
    int*   cursor  = (int*)carve(sizeof(int) * KK * NN);
    int4*  segs    = (int4*)carve(sizeof(int4) * NN);
    int*   csr_comb= (int*)carve(sizeof(int) * (CSR_CAP + 80));

    hipMemsetAsync(counts, 0, sizeof(int) * KK * NN, stream);

    prep_alc<<<KK * HH, 64, 0, stream>>>(fc_w, attn_l, attn_r, alc, arc);

    init_pad_kernel<<<6, 256, 0, stream>>>(featp, elp);

    feat_kernel<<<KK * NN, 128, 0, stream>>>(x, fc_w, alc, arc, featp, elp, er);

    int edgeBlocks = (KK * ETOT + 255) / 256;
    count_kernel<<<edgeBlocks, 256, 0, stream>>>(dst_idx, counts);
    scan_kernel<<<1, 1024, 0, stream>>>(counts, segs, cursor, csr_comb);
    scatter_kernel<<<edgeBlocks, 256, 0, stream>>>(src_idx, dst_idx, cursor, csr_comb);

    agg_kernel<<<24 * 256, 256, 0, stream>>>(
        featp, elp, er, segs, csr_comb, gat_bias, weight, gat);

    merge_kernel<<<NN * 6, 128, 0, stream>>>(gat, merge_w, merge_b, x, out);
}

// Round 10
// 198.893 us; speedup vs baseline: 1.3921x; 1.1255x over previous
//
#include <hip/hip_runtime.h>

#define NN   1024
#define TT   12
#define CC   64
#define DD   64
#define HH   2
#define KK   3
#define ETOT 17408           // E (16384) + N self loops
#define BT   48              // B*T
#define BTH  96              // B*T*H
#define HD   128             // H*D
#define NODES (KK * NN + 1)  // +1 sentinel pad node (feat=0, el=-inf)
#define PADN  (KK * NN)
#define CSR_CAP (KK * ETOT + 12 * NN)   // segments padded to x4
#define LOG2E 1.44269504f
#define MTILE 128
#define NBLK  (NN * BT / MTILE)         // 384 M-tiles per k

__device__ __forceinline__ float bf_lo(unsigned int u) {
    return __uint_as_float(u << 16);
}
__device__ __forceinline__ float bf_hi(unsigned int u) {
    return __uint_as_float(u & 0xFFFF0000u);
}
__device__ __forceinline__ unsigned short f2bf(float f) {
    unsigned int u = __float_as_uint(f);
    u += 0x7FFFu + ((u >> 16) & 1u);      // round-to-nearest-even
    return (unsigned short)(u >> 16);
}
__device__ __forceinline__ unsigned int pack2(float a, float b) {
    return (unsigned int)f2bf(a) | ((unsigned int)f2bf(b) << 16);
}
__device__ __forceinline__ float rlf(float v, int lane) {
    return __int_as_float(__builtin_amdgcn_readlane(__float_as_int(v), lane));
}

// ---------------- Pass 0: alc/arc = log2e * (fc_w @ attn_{l,r})  [K,H,C] ----
__global__ __launch_bounds__(64) void prep_alc(
    const float* __restrict__ fc_w, const float* __restrict__ attn_l,
    const float* __restrict__ attn_r, float* __restrict__ alc, float* __restrict__ arc)
{
    int kh = blockIdx.x;            // 0..5
    int k = kh >> 1, h = kh & 1;
    int c = threadIdx.x;            // 0..63
    float sl = 0.f, sr = 0.f;
    #pragma unroll
    for (int d = 0; d < 64; ++d) {
        float w = fc_w[k * CC * HD + c * HD + h * 64 + d];
        sl = fmaf(w, attn_l[k * HD + h * 64 + d], sl);
        sr = fmaf(w, attn_r[k * HD + h * 64 + d], sr);
    }
    alc[kh * 64 + c] = sl * LOG2E;
    arc[kh * 64 + c] = sr * LOG2E;
}

// ---------------- Pass A1: feat = x @ fc_w as tiled GEMM (bf16 out) ---------
// M = n*48+bt (49152), tile 128 rows x full N=128. Thread: 8x8 register tile.
// featp (uint2): [s=(btg4*2+h)][node=k*NN+n][d], uint2 = bt btg4*4+0..3 (bf16)
__global__ __launch_bounds__(256) void feat_tiled_kernel(
    const float* __restrict__ x,       // [B,N,T,C]
    const float* __restrict__ fc_w,    // [K,C,HD]
    uint2* __restrict__ featp)
{
    int k  = blockIdx.x / NBLK;
    int m0 = (blockIdx.x - k * NBLK) * MTILE;
    int t  = threadIdx.x;              // 0..255

    __shared__ __align__(16) float smem[16384];   // 64 KB
    float* xs = smem;                  // [c=0..63][mi=0..127] column-major
    float* ws = smem + 8192;           // [c=0..63][e=0..127] row-major

    // fill W (straight copy, coalesced, conflict-free)
    #pragma unroll
    for (int r = 0; r < 32; ++r) {
        int idx = t + 256 * r;         // 0..8191
        ws[idx] = fc_w[k * CC * HD + idx];
    }
    // fill x transposed: thread loads float4 along c, scatters 4 LDS stores
    #pragma unroll
    for (int r = 0; r < 8; ++r) {
        int idx = t + 256 * r;         // 0..2047
        int mi = idx >> 4, c4 = idx & 15;
        int m  = m0 + mi;
        int n  = m / BT, bt = m - n * BT;
        int b  = bt / TT, tt = bt - b * TT;
        float4 v = *(const float4*)&x[(((size_t)b * NN + n) * TT + tt) * CC + c4 * 4];
        xs[(c4 * 4 + 0) * MTILE + mi] = v.x;
        xs[(c4 * 4 + 1) * MTILE + mi] = v.y;
        xs[(c4 * 4 + 2) * MTILE + mi] = v.z;
        xs[(c4 * 4 + 3) * MTILE + mi] = v.w;
    }
    __syncthreads();

    int mi0 = (t & 15) * 8;            // 8 rows (within one n: 48%8==0)
    int e0  = (t >> 4) * 8;            // 8 cols

    float acc[8][8];
    #pragma unroll
    for (int i = 0; i < 8; ++i)
        #pragma unroll
        for (int jj = 0; jj < 8; ++jj) acc[i][jj] = 0.f;

    #pragma unroll 4
    for (int c = 0; c < CC; ++c) {
        float4 xa = *(const float4*)&xs[c * MTILE + mi0];
        float4 xb = *(const float4*)&xs[c * MTILE + mi0 + 4];
        float4 wa = *(const float4*)&ws[c * HD + e0];
        float4 wb = *(const float4*)&ws[c * HD + e0 + 4];
        float xv[8] = {xa.x, xa.y, xa.z, xa.w, xb.x, xb.y, xb.z, xb.w};
        float wv[8] = {wa.x, wa.y, wa.z, wa.w, wb.x, wb.y, wb.z, wb.w};
        #pragma unroll
        for (int i = 0; i < 8; ++i)
            #pragma unroll
            for (int jj = 0; jj < 8; ++jj)
                acc[i][jj] = fmaf(xv[i], wv[jj], acc[i][jj]);
    }
    __syncthreads();                   // xs/ws dead; reuse as output staging

    // stage packed bf16 output: outb[rg=0..31][e=0..127] (row = 4-bt chunk)
    uint2* outb = (uint2*)smem;        // 32 x 130 uint2 = 33.3 KB
    #pragma unroll
    for (int g = 0; g < 2; ++g) {
        int rg = (t & 15) * 2 + g;
        #pragma unroll
        for (int jj = 0; jj < 8; ++jj) {
            outb[rg * 130 + e0 + jj] = make_uint2(
                pack2(acc[g * 4 + 0][jj], acc[g * 4 + 1][jj]),
                pack2(acc[g * 4 + 2][jj], acc[g * 4 + 3][jj]));
        }
    }
    __syncthreads();

    // coalesced slice-major writes: 64 runs of 512B
    #pragma unroll
    for (int rep = 0; rep < 16; ++rep) {
        int idx = t + 256 * rep;       // 0..4095
        int run = idx >> 6;            // 0..63
        int l   = idx & 63;
        int rg = run >> 1, h = run & 1;
        int m  = m0 + rg * 4;
        int n  = m / BT;
        int btL = m - n * BT;
        int s = (btL >> 2) * 2 + h;
        featp[((size_t)s * NODES + k * NN + n) * 64 + l] = outb[rg * 130 + h * 64 + l];
    }
}

// ---------------- Pass A2: el/er (tiny GEMV per n) ---------------------------
__global__ __launch_bounds__(128) void elr_kernel(
    const float* __restrict__ x, const float* __restrict__ alc,
    const float* __restrict__ arc, float* __restrict__ elp, float* __restrict__ er)
{
    int n = blockIdx.x;
    int e = threadIdx.x;               // 0..127
    __shared__ float x_lds[BT * CC];   // 12 KB
    __shared__ float cl[KK * HH * CC]; // 1.5 KB
    __shared__ float cr[KK * HH * CC];

    for (int i = e; i < BT * CC; i += 128) {
        int bt = i >> 6, c = i & 63;
        int b = bt / TT, tt = bt - b * TT;
        x_lds[i] = x[(((size_t)b * NN + n) * TT + tt) * CC + c];
    }
    for (int i = e; i < KK * HH * CC; i += 128) { cl[i] = alc[i]; cr[i] = arc[i]; }
    __syncthreads();

    if (e < BTH) {
        int hh = e / BT, bt = e - hh * BT;
        #pragma unroll
        for (int k = 0; k < KK; ++k) {
            const float* alp = &cl[(k * HH + hh) * CC];
            const float* arp = &cr[(k * HH + hh) * CC];
            float sl = 0.f, sr = 0.f;
            #pragma unroll
            for (int cc = 0; cc < CC; ++cc) {
                int c = (cc + bt) & 63;        // stagger: conflict-free
                float xv = x_lds[bt * CC + c];
                sl = fmaf(xv, alp[c], sl);
                sr = fmaf(xv, arp[c], sr);
            }
            int s = (bt >> 2) * 2 + hh;
            elp[((size_t)s * NODES + k * NN + n) * 4 + (bt & 3)] = sl;
            er[((size_t)(k * NN + n)) * BTH + e] = sr;
        }
    }
}

// ---------------- pad-node init ---------------------------------------------
__global__ void init_pad_kernel(uint2* __restrict__ featp, float* __restrict__ elp)
{
    int t = blockIdx.x * 256 + threadIdx.x;
    if (t < 24 * 64) {
        int s = t >> 6, dd = t & 63;
        featp[((size_t)s * NODES + PADN) * 64 + dd] = make_uint2(0u, 0u);
    }
    if (t < 24 * 4) {
        int s = t >> 2, i = t & 3;
        elp[((size_t)s * NODES + PADN) * 4 + i] = -1e30f;   // alpha = 0 exactly
    }
}

// ---------------- CSR build (per-(k,n) segments, padded to 4) ---------------
__global__ void count_kernel(const int* __restrict__ dst_idx, int* __restrict__ counts)
{
    int tid = blockIdx.x * blockDim.x + threadIdx.x;
    if (tid < KK * ETOT) {
        int k = tid / ETOT;
        atomicAdd(&counts[k * NN + dst_idx[tid]], 1);
    }
}

__global__ __launch_bounds__(1024) void scan_kernel(
    const int* __restrict__ counts,
    int4* __restrict__ segs,         // [NN]: {s0, s1, s2, end}
    int* __restrict__ cursor,        // [K*NN]
    int* __restrict__ csr_comb)      // pad entries -> PADN
{
    int n = threadIdx.x;
    int c0 = counts[n], c1 = counts[NN + n], c2 = counts[2 * NN + n];
    int p0 = (c0 + 3) & ~3, p1 = (c1 + 3) & ~3, p2 = (c2 + 3) & ~3;
    int tot = p0 + p1 + p2;
    __shared__ int buf[NN];
    buf[n] = tot;
    __syncthreads();
    for (int off = 1; off < NN; off <<= 1) {
        int v = (n >= off) ? buf[n - off] : 0;
        __syncthreads();
        buf[n] += v;
        __syncthreads();
    }
    int excl = buf[n] - tot;
    int4 sg;
    sg.x = excl; sg.y = excl + p0; sg.z = excl + p0 + p1; sg.w = excl + tot;
    segs[n] = sg;
    cursor[n] = sg.x;
    cursor[NN + n] = sg.y;
    cursor[2 * NN + n] = sg.z;
    for (int j = sg.x + c0; j < sg.y; ++j) csr_comb[j] = PADN;
    for (int j = sg.y + c1; j < sg.z; ++j) csr_comb[j] = PADN;
    for (int j = sg.z + c2; j < sg.w; ++j) csr_comb[j] = PADN;
}

__global__ void scatter_kernel(const int* __restrict__ src_idx,
                               const int* __restrict__ dst_idx,
                               int* __restrict__ cursor, int* __restrict__ csr_comb)
{
    int tid = blockIdx.x * blockDim.x + threadIdx.x;
    if (tid < KK * ETOT) {
        int k = tid / ETOT;
        int pos = atomicAdd(&cursor[k * NN + dst_idx[tid]], 1);
        csr_comb[pos] = k * NN + src_idx[tid];
    }
}

// ---------------- Pass D: fused softmax + aggregate, slice-pinned to XCDs ---
__global__ __launch_bounds__(256) void agg_kernel(
    const uint2* __restrict__ featp,
    const float* __restrict__ elp,
    const float* __restrict__ er,
    const int4* __restrict__ segs, const int* __restrict__ csr_comb,
    const float* __restrict__ gat_bias, const float* __restrict__ weight,
    float* __restrict__ gat)           // [n][bt][HD] f32
{
    int j = ((int)blockIdx.x >> 3) + 768 * ((int)blockIdx.x & 7);
    int s = j >> 8;                    // 0..23
    int g = j & 255;
    int w = threadIdx.x >> 6;          // 0..3
    int d = threadIdx.x & 63;          // lane
    int n = g * 4 + w;
    int btg4 = s >> 1, h = s & 1;
    int e = h * 64 + d;

    const uint2* fb = featp + (size_t)s * NODES * 64 + d;
    const float* ep = elp + (size_t)s * NODES * 4;
    int4 sg = segs[n];

    float acc0 = 0.f, acc1 = 0.f, acc2 = 0.f, acc3 = 0.f;

    #pragma unroll
    for (int k = 0; k < KK; ++k) {
        int jb = (k == 0) ? sg.x : (k == 1) ? sg.y : sg.z;
        int je = (k == 0) ? sg.y : (k == 1) ? sg.z : sg.w;
        float4 er4 = *(const float4*)&er[((size_t)(k * NN + n)) * BTH + h * BT + btg4 * 4];

        float ss0 = 0.f, ss1 = 0.f, ss2 = 0.f, ss3 = 0.f;
        float r0 = 0.f, r1 = 0.f, r2 = 0.f, r3 = 0.f;

        for (int j0 = jb; j0 < je; j0 += 64) {
            int lj = j0 + d;
            int idx = PADN;
            if (lj < je) idx = csr_comb[lj];
            float4 ev = *(const float4*)&ep[idx * 4];
            float t0 = ev.x + er4.x, t1 = ev.y + er4.y;
            float t2 = ev.z + er4.z, t3 = ev.w + er4.w;
            t0 = fmaxf(t0, t0 * 0.2f); t1 = fmaxf(t1, t1 * 0.2f);
            t2 = fmaxf(t2, t2 * 0.2f); t3 = fmaxf(t3, t3 * 0.2f);
            float a0 = __builtin_amdgcn_exp2f(t0);
            float a1 = __builtin_amdgcn_exp2f(t1);
            float a2 = __builtin_amdgcn_exp2f(t2);
            float a3 = __builtin_amdgcn_exp2f(t3);
            ss0 += a0; ss1 += a1; ss2 += a2; ss3 += a3;

            int mm = je - j0; if (mm > 64) mm = 64;    // multiple of 4
            for (int u = 0; u < mm; u += 4) {
                int i0 = __builtin_amdgcn_readlane(idx, u + 0);
                int i1 = __builtin_amdgcn_readlane(idx, u + 1);
                int i2 = __builtin_amdgcn_readlane(idx, u + 2);
                int i3 = __builtin_amdgcn_readlane(idx, u + 3);
                uint2 f0 = fb[(size_t)i0 * 64];
                uint2 f1 = fb[(size_t)i1 * 64];
                uint2 f2 = fb[(size_t)i2 * 64];
                uint2 f3 = fb[(size_t)i3 * 64];

                float p0 = rlf(a0, u + 0), p1 = rlf(a1, u + 0),
                      p2 = rlf(a2, u + 0), p3 = rlf(a3, u + 0);
                r0 = fmaf(p0, bf_lo(f0.x), r0); r1 = fmaf(p1, bf_hi(f0.x), r1);
                r2 = fmaf(p2, bf_lo(f0.y), r2); r3 = fmaf(p3, bf_hi(f0.y), r3);

                p0 = rlf(a0, u + 1); p1 = rlf(a1, u + 1);
                p2 = rlf(a2, u + 1); p3 = rlf(a3, u + 1);
                r0 = fmaf(p0, bf_lo(f1.x), r0); r1 = fmaf(p1, bf_hi(f1.x), r1);
                r2 = fmaf(p2, bf_lo(f1.y), r2); r3 = fmaf(p3, bf_hi(f1.y), r3);

                p0 = rlf(a0, u + 2); p1 = rlf(a1, u + 2);
                p2 = rlf(a2, u + 2); p3 = rlf(a3, u + 2);
                r0 = fmaf(p0, bf_lo(f2.x), r0); r1 = fmaf(p1, bf_hi(f2.x), r1);
                r2 = fmaf(p2, bf_lo(f2.y), r2); r3 = fmaf(p3, bf_hi(f2.y), r3);

                p0 = rlf(a0, u + 3); p1 = rlf(a1, u + 3);
                p2 = rlf(a2, u + 3); p3 = rlf(a3, u + 3);
                r0 = fmaf(p0, bf_lo(f3.x), r0); r1 = fmaf(p1, bf_hi(f3.x), r1);
                r2 = fmaf(p2, bf_lo(f3.y), r2); r3 = fmaf(p3, bf_hi(f3.y), r3);
            }
        }

        #pragma unroll
        for (int off = 1; off < 64; off <<= 1) {
            ss0 += __shfl_xor(ss0, off, 64);
            ss1 += __shfl_xor(ss1, off, 64);
            ss2 += __shfl_xor(ss2, off, 64);
            ss3 += __shfl_xor(ss3, off, 64);
        }
        float wk = weight[k];
        acc0 = fmaf(r0, wk * __builtin_amdgcn_rcpf(ss0), acc0);
        acc1 = fmaf(r1, wk * __builtin_amdgcn_rcpf(ss1), acc1);
        acc2 = fmaf(r2, wk * __builtin_amdgcn_rcpf(ss2), acc2);
        acc3 = fmaf(r3, wk * __builtin_amdgcn_rcpf(ss3), acc3);
    }

    float wb = weight[0] * gat_bias[e] + weight[1] * gat_bias[HD + e]
             + weight[2] * gat_bias[2 * HD + e];
    acc0 += wb; acc1 += wb; acc2 += wb; acc3 += wb;

    gat[((size_t)n * BT + btg4 * 4 + 0) * HD + e] = acc0;
    gat[((size_t)n * BT + btg4 * 4 + 1) * HD + e] = acc1;
    gat[((size_t)n * BT + btg4 * 4 + 2) * HD + e] = acc2;
    gat[((size_t)n * BT + btg4 * 4 + 3) * HD + e] = acc3;
}

// ---------------- Pass E: merge GEMV + leakyrelu + residual -----------------
__global__ __launch_bounds__(128) void merge_kernel(
    const float* __restrict__ gat,
    const float* __restrict__ merge_w, const float* __restrict__ merge_b,
    const float* __restrict__ x, float* __restrict__ out)
{
    int m = blockIdx.x >> 10;        // 0..5 (8-bt group)
    int n = blockIdx.x & 1023;
    int e = threadIdx.x;             // 0..127

    __shared__ float rows[8][HD];    // 4 KB
    #pragma unroll
    for (int i = 0; i < 8; ++i)
        rows[i][e] = gat[((size_t)n * BT + m * 8 + i) * HD + e];
    __syncthreads();

    #pragma unroll
    for (int pass = 0; pass < 4; ++pass) {
        int oi = pass * 128 + e;     // 512 outputs: 8 rows x 64 cols
        int rr = oi >> 6, dd = oi & 63;
        float mg = merge_b[dd];
        #pragma unroll
        for (int q = 0; q < HD; ++q) mg = fmaf(rows[rr][q], merge_w[q * DD + dd], mg);
        mg = mg > 0.f ? mg : mg * 0.01f;
        int bt = m * 8 + rr;
        int b = bt / TT, t = bt - b * TT;
        size_t oidx = (((size_t)b * NN + n) * TT + t) * DD + dd;
        out[oidx] = mg + x[oidx];
    }
}

extern "C" void kernel_launch(void* const* d_in, const int* in_sizes, int n_in,
                              void* d_out, int out_size, void* d_ws, size_t ws_size,
                              hipStream_t stream)
{
    const float* x        = (const float*)d_in[0];
    const float* fc_w     = (const float*)d_in[1];
    const float* attn_l   = (const float*)d_in[2];
    const float* attn_r   = (const float*)d_in[3];
    const float* gat_bias = (const float*)d_in[4];
    const float* weight   = (const float*)d_in[5];
    const float* merge_w  = (const float*)d_in[6];
    const float* merge_b  = (const float*)d_in[7];
    const int*   src_idx  = (const int*)d_in[8];
    const int*   dst_idx  = (const int*)d_in[9];
    float*       out      = (float*)d_out;

    char* p = (char*)d_ws;
    auto carve = [&](size_t bytes) { char* r = p; p += (bytes + 15) & ~size_t(15); return r; };
    uint2* featp   = (uint2*)carve(sizeof(uint2) * (size_t)24 * NODES * 64);   // 37.8 MB
    float* elp     = (float*)carve(sizeof(float) * (size_t)24 * NODES * 4);    // 1.18 MB
    float* er      = (float*)carve(sizeof(float) * (size_t)KK * NN * BTH);     // 1.18 MB
    float* gat     = (float*)carve(sizeof(float) * (size_t)NN * BT * HD);      // 25.2 MB
    float* alc     = (float*)carve(sizeof(float) * KK * HH * CC);
    float* arc     = (float*)carve(sizeof(float) * KK * HH * CC);
    int*   counts  = (int*)carve(sizeof(int) * KK * NN);
    int*   cursor  = (int*)carve(sizeof(int) * KK * NN);
    int4*  segs    = (int4*)carve(sizeof(int4) * NN);
    int*   csr_comb= (int*)carve(sizeof(int) * (CSR_CAP + 80));

    hipMemsetAsync(counts, 0, sizeof(int) * KK * NN, stream);

    prep_alc<<<KK * HH, 64, 0, stream>>>(fc_w, attn_l, attn_r, alc, arc);

    init_pad_kernel<<<6, 256, 0, stream>>>(featp, elp);

    feat_tiled_kernel<<<KK * NBLK, 256, 0, stream>>>(x, fc_w, featp);

    elr_kernel<<<NN, 128, 0, stream>>>(x, alc, arc, elp, er);

    int edgeBlocks = (KK * ETOT + 255) / 256;
    count_kernel<<<edgeBlocks, 256, 0, stream>>>(dst_idx, counts);
    scan_kernel<<<1, 1024, 0, stream>>>(counts, segs, cursor, csr_comb);
    scatter_kernel<<<edgeBlocks, 256, 0, stream>>>(src_idx, dst_idx, cursor, csr_comb);

    agg_kernel<<<24 * 256, 256, 0, stream>>>(
        featp, elp, er, segs, csr_comb, gat_bias, weight, gat);

    merge_kernel<<<NN * 6, 128, 0, stream>>>(gat, merge_w, merge_b, x, out);
}

// Round 11
// 168.160 us; speedup vs baseline: 1.6465x; 1.1828x over previous
//
#include <hip/hip_runtime.h>

#define NN   1024
#define TT   12
#define CC   64
#define DD   64
#define HH   2
#define KK   3
#define ETOT 17408           // E (16384) + N self loops
#define BT   48              // B*T
#define BTH  96              // B*T*H
#define HD   128             // H*D
#define NODES (KK * NN + 1)  // +1 sentinel pad node (feat=0, el=-inf)
#define PADN  (KK * NN)
#define CSR_CAP (KK * ETOT + 12 * NN)   // segments padded to x4
#define LOG2E 1.44269504f
#define MT   128                         // feat GEMM M-tile
#define NBLK (NN * BT / MT)              // 384 M-tiles per k
#define EDGE_BLOCKS ((KK * ETOT + 255) / 256)   // 204

typedef __attribute__((ext_vector_type(8))) short s8v;    // 8 bf16
typedef __attribute__((ext_vector_type(4))) float f4v;    // 4 f32 acc

__device__ __forceinline__ float bf_lo(unsigned int u) {
    return __uint_as_float(u << 16);
}
__device__ __forceinline__ float bf_hi(unsigned int u) {
    return __uint_as_float(u & 0xFFFF0000u);
}
__device__ __forceinline__ unsigned short f2bf(float f) {
    unsigned int u = __float_as_uint(f);
    u += 0x7FFFu + ((u >> 16) & 1u);      // round-to-nearest-even
    return (unsigned short)(u >> 16);
}
__device__ __forceinline__ unsigned int pack2(float a, float b) {
    return (unsigned int)f2bf(a) | ((unsigned int)f2bf(b) << 16);
}

// ---------------- aux: count (blocks 0..203) + prep_alc + pad-init ----------
__global__ __launch_bounds__(256) void aux_kernel(
    const int* __restrict__ dst_idx, int* __restrict__ counts,
    const float* __restrict__ fc_w, const float* __restrict__ attn_l,
    const float* __restrict__ attn_r, float* __restrict__ alc, float* __restrict__ arc,
    uint2* __restrict__ featp, float* __restrict__ elp)
{
    int bid = blockIdx.x;
    int t = threadIdx.x;
    if (bid < EDGE_BLOCKS) {
        int tid = bid * 256 + t;
        if (tid < KK * ETOT) {
            int k = tid / ETOT;
            atomicAdd(&counts[k * NN + dst_idx[tid]], 1);
        }
    } else {
        for (int item = t; item < KK * HH * CC; item += 256) {   // prep_alc
            int kh = item >> 6, c = item & 63;
            int k = kh >> 1, h = kh & 1;
            float sl = 0.f, sr = 0.f;
            #pragma unroll
            for (int dd = 0; dd < 64; ++dd) {
                float wv = fc_w[k * CC * HD + c * HD + h * 64 + dd];
                sl = fmaf(wv, attn_l[k * HD + h * 64 + dd], sl);
                sr = fmaf(wv, attn_r[k * HD + h * 64 + dd], sr);
            }
            alc[item] = sl * LOG2E;
            arc[item] = sr * LOG2E;
        }
        for (int item = t; item < 24 * 64; item += 256)          // feat pad node
            featp[((size_t)(item >> 6) * NODES + PADN) * 64 + (item & 63)] = make_uint2(0u, 0u);
        for (int item = t; item < 24 * 4; item += 256)           // elp pad node
            elp[((size_t)(item >> 2) * NODES + PADN) * 4 + (item & 3)] = -1e30f;
    }
}

// ---------------- Pass A1: feat = x @ fc_w via bf16 MFMA --------------------
// Block: 128M x 128N, 4 waves (each 64M x 64N), K=64 (2 mfma k-steps).
// featp (uint2): [s=(btg4*2+h)][node=k*NN+n][d], uint2 = bts btg4*4+0..3 (bf16)
__global__ __launch_bounds__(256) void feat_mfma_kernel(
    const float* __restrict__ x,       // [B,N,T,C]
    const float* __restrict__ fc_w,    // [K,C,HD]
    uint2* __restrict__ featp)
{
    int k  = blockIdx.x / NBLK;
    int m0 = (blockIdx.x - k * NBLK) * MT;
    int t  = threadIdx.x;              // 0..255
    int w  = t >> 6, l = t & 63;

    __shared__ __align__(16) unsigned short As[128 * 64];  // x tile bf16 [row][c], swz
    __shared__ __align__(16) unsigned short Ws[128 * 64];  // W^T bf16 [e][c], swz

    // stage A: row = m-tile row, 8 c-groups of 8 (16B), group-XOR swizzle
    #pragma unroll
    for (int rep = 0; rep < 4; ++rep) {
        int gid = t + 256 * rep;       // 0..1023
        int row = gid >> 3, g = gid & 7;
        int m = m0 + row;
        int n = m / BT, bt = m - n * BT;
        int b = bt / TT, tt2 = bt - b * TT;
        const float* xr = &x[(((size_t)b * NN + n) * TT + tt2) * CC + g * 8];
        float4 v0 = *(const float4*)xr;
        float4 v1 = *(const float4*)(xr + 4);
        uint4 pk = { pack2(v0.x, v0.y), pack2(v0.z, v0.w),
                     pack2(v1.x, v1.y), pack2(v1.z, v1.w) };
        *(uint4*)((char*)As + row * 128 + ((g ^ (row & 7)) << 4)) = pk;
    }
    // stage W^T: row = e, 8 c-groups
    #pragma unroll
    for (int rep = 0; rep < 4; ++rep) {
        int gid = t + 256 * rep;
        int e = gid & 127, g = gid >> 7;          // g advances with rep
        float v[8];
        #pragma unroll
        for (int jj = 0; jj < 8; ++jj)
            v[jj] = fc_w[(size_t)k * CC * HD + (g * 8 + jj) * HD + e];
        uint4 pk = { pack2(v[0], v[1]), pack2(v[2], v[3]),
                     pack2(v[4], v[5]), pack2(v[6], v[7]) };
        *(uint4*)((char*)Ws + e * 128 + ((g ^ (e & 7)) << 4)) = pk;
    }
    __syncthreads();

    int Mw = (w & 1) * 64;
    int Nw = (w >> 1) * 64;
    int rsel = l & 15, ksel = l >> 4;  // ksel 0..3

    f4v acc[4][4];
    #pragma unroll
    for (int mi = 0; mi < 4; ++mi)
        #pragma unroll
        for (int nf = 0; nf < 4; ++nf)
            acc[mi][nf] = (f4v){0.f, 0.f, 0.f, 0.f};

    s8v af[4][2], bf[4][2];
    #pragma unroll
    for (int mi = 0; mi < 4; ++mi)
        #pragma unroll
        for (int ks = 0; ks < 2; ++ks) {
            int row = Mw + mi * 16 + rsel;
            int g = ks * 4 + ksel;
            af[mi][ks] = *(const s8v*)((const char*)As + row * 128 + ((g ^ (row & 7)) << 4));
        }
    #pragma unroll
    for (int nf = 0; nf < 4; ++nf)
        #pragma unroll
        for (int ks = 0; ks < 2; ++ks) {
            int e = Nw + nf * 16 + rsel;
            int g = ks * 4 + ksel;
            bf[nf][ks] = *(const s8v*)((const char*)Ws + e * 128 + ((g ^ (e & 7)) << 4));
        }

    #pragma unroll
    for (int mi = 0; mi < 4; ++mi)
        #pragma unroll
        for (int nf = 0; nf < 4; ++nf) {
            acc[mi][nf] = __builtin_amdgcn_mfma_f32_16x16x32_bf16(
                af[mi][0], bf[nf][0], acc[mi][nf], 0, 0, 0);
            acc[mi][nf] = __builtin_amdgcn_mfma_f32_16x16x32_bf16(
                af[mi][1], bf[nf][1], acc[mi][nf], 0, 0, 0);
        }

    // epilogue: D layout col=lane&15, row=(lane>>4)*4+reg -> one uint2 per frag
    int i0 = (l >> 4) * 4;
    #pragma unroll
    for (int mi = 0; mi < 4; ++mi) {
        int m = m0 + Mw + mi * 16 + i0;          // 4 consecutive bts (m%4==0)
        int n = m / BT, bt = m - n * BT;
        #pragma unroll
        for (int nf = 0; nf < 4; ++nf) {
            int e = Nw + nf * 16 + (l & 15);
            int h = e >> 6, d = e & 63;
            int s = (bt >> 2) * 2 + h;
            uint2 o = { pack2(acc[mi][nf][0], acc[mi][nf][1]),
                        pack2(acc[mi][nf][2], acc[mi][nf][3]) };
            featp[((size_t)s * NODES + k * NN + n) * 64 + d] = o;
        }
    }
}

// ---------------- Pass A2: el/er (tiny GEMV per n) ---------------------------
__global__ __launch_bounds__(128) void elr_kernel(
    const float* __restrict__ x, const float* __restrict__ alc,
    const float* __restrict__ arc, float* __restrict__ elp, float* __restrict__ er)
{
    int n = blockIdx.x;
    int e = threadIdx.x;               // 0..127
    __shared__ float x_lds[BT * CC];   // 12 KB
    __shared__ float cl[KK * HH * CC];
    __shared__ float cr[KK * HH * CC];

    for (int i = e; i < BT * CC; i += 128) {
        int bt = i >> 6, c = i & 63;
        int b = bt / TT, tt = bt - b * TT;
        x_lds[i] = x[(((size_t)b * NN + n) * TT + tt) * CC + c];
    }
    for (int i = e; i < KK * HH * CC; i += 128) { cl[i] = alc[i]; cr[i] = arc[i]; }
    __syncthreads();

    if (e < BTH) {
        int hh = e / BT, bt = e - hh * BT;
        #pragma unroll
        for (int k = 0; k < KK; ++k) {
            const float* alp = &cl[(k * HH + hh) * CC];
            const float* arp = &cr[(k * HH + hh) * CC];
            float sl = 0.f, sr = 0.f;
            #pragma unroll
            for (int cc = 0; cc < CC; ++cc) {
                int c = (cc + bt) & 63;        // stagger: conflict-free
                float xv = x_lds[bt * CC + c];
                sl = fmaf(xv, alp[c], sl);
                sr = fmaf(xv, arp[c], sr);
            }
            int s = (bt >> 2) * 2 + hh;
            elp[((size_t)s * NODES + k * NN + n) * 4 + (bt & 3)] = sl;
            er[((size_t)(k * NN + n)) * BTH + e] = sr;
        }
    }
}

// ---------------- CSR build (per-(k,n) segments, padded to 4) ---------------
__global__ __launch_bounds__(1024) void scan_kernel(
    const int* __restrict__ counts,
    int4* __restrict__ segs,         // [NN]: {s0, s1, s2, end}
    int* __restrict__ cursor,        // [K*NN]
    int* __restrict__ csr_comb)      // pad entries -> PADN
{
    int n = threadIdx.x;
    int c0 = counts[n], c1 = counts[NN + n], c2 = counts[2 * NN + n];
    int p0 = (c0 + 3) & ~3, p1 = (c1 + 3) & ~3, p2 = (c2 + 3) & ~3;
    int tot = p0 + p1 + p2;
    __shared__ int buf[NN];
    buf[n] = tot;
    __syncthreads();
    for (int off = 1; off < NN; off <<= 1) {
        int v = (n >= off) ? buf[n - off] : 0;
        __syncthreads();
        buf[n] += v;
        __syncthreads();
    }
    int excl = buf[n] - tot;
    int4 sg;
    sg.x = excl; sg.y = excl + p0; sg.z = excl + p0 + p1; sg.w = excl + tot;
    segs[n] = sg;
    cursor[n] = sg.x;
    cursor[NN + n] = sg.y;
    cursor[2 * NN + n] = sg.z;
    for (int j = sg.x + c0; j < sg.y; ++j) csr_comb[j] = PADN;
    for (int j = sg.y + c1; j < sg.z; ++j) csr_comb[j] = PADN;
    for (int j = sg.z + c2; j < sg.w; ++j) csr_comb[j] = PADN;
}

__global__ void scatter_kernel(const int* __restrict__ src_idx,
                               const int* __restrict__ dst_idx,
                               int* __restrict__ cursor, int* __restrict__ csr_comb)
{
    int tid = blockIdx.x * blockDim.x + threadIdx.x;
    if (tid < KK * ETOT) {
        int k = tid / ETOT;
        int pos = atomicAdd(&cursor[k * NN + dst_idx[tid]], 1);
        csr_comb[pos] = k * NN + src_idx[tid];
    }
}

// ---------------- Pass D: fused softmax + aggregate, slice-pinned to XCDs ---
__global__ __launch_bounds__(256) void agg_kernel(
    const uint2* __restrict__ featp,
    const float* __restrict__ elp,
    const float* __restrict__ er,
    const int4* __restrict__ segs, const int* __restrict__ csr_comb,
    const float* __restrict__ gat_bias, const float* __restrict__ weight,
    float* __restrict__ gat)           // [n][bt][HD] f32
{
    int j = ((int)blockIdx.x >> 3) + 768 * ((int)blockIdx.x & 7);
    int s = j >> 8;                    // 0..23
    int g = j & 255;
    int w = threadIdx.x >> 6;          // 0..3
    int d = threadIdx.x & 63;          // lane
    int n = g * 4 + w;
    int btg4 = s >> 1, h = s & 1;
    int e = h * 64 + d;

    __shared__ __align__(16) float alds[4][64][4];   // per-wave alpha staging

    const uint2* fb = featp + (size_t)s * NODES * 64 + d;
    const float* ep = elp + (size_t)s * NODES * 4;
    int4 sg = segs[n];

    float acc0 = 0.f, acc1 = 0.f, acc2 = 0.f, acc3 = 0.f;

    #pragma unroll
    for (int k = 0; k < KK; ++k) {
        int jb = (k == 0) ? sg.x : (k == 1) ? sg.y : sg.z;
        int je = (k == 0) ? sg.y : (k == 1) ? sg.z : sg.w;
        float4 er4 = *(const float4*)&er[((size_t)(k * NN + n)) * BTH + h * BT + btg4 * 4];

        float ss0 = 0.f, ss1 = 0.f, ss2 = 0.f, ss3 = 0.f;
        float r0 = 0.f, r1 = 0.f, r2 = 0.f, r3 = 0.f;

        for (int j0 = jb; j0 < je; j0 += 64) {
            // ---- batch phase: lane L computes alphas for edge j0+L ----
            int lj = j0 + d;
            int idx = PADN;
            if (lj < je) idx = csr_comb[lj];
            float4 ev = *(const float4*)&ep[idx * 4];
            float t0 = ev.x + er4.x, t1 = ev.y + er4.y;
            float t2 = ev.z + er4.z, t3 = ev.w + er4.w;
            t0 = fmaxf(t0, t0 * 0.2f); t1 = fmaxf(t1, t1 * 0.2f);
            t2 = fmaxf(t2, t2 * 0.2f); t3 = fmaxf(t3, t3 * 0.2f);
            float a0 = __builtin_amdgcn_exp2f(t0);
            float a1 = __builtin_amdgcn_exp2f(t1);
            float a2 = __builtin_amdgcn_exp2f(t2);
            float a3 = __builtin_amdgcn_exp2f(t3);
            ss0 += a0; ss1 += a1; ss2 += a2; ss3 += a3;
            *(float4*)&alds[w][d][0] = make_float4(a0, a1, a2, a3);  // same-wave RAW

            // ---- FMA phase: idx via readlane (scalar addr), alpha via LDS ----
            int mm = je - j0; if (mm > 64) mm = 64;    // multiple of 4
            for (int u = 0; u < mm; u += 4) {
                int i0 = __builtin_amdgcn_readlane(idx, u + 0);
                int i1 = __builtin_amdgcn_readlane(idx, u + 1);
                int i2 = __builtin_amdgcn_readlane(idx, u + 2);
                int i3 = __builtin_amdgcn_readlane(idx, u + 3);
                uint2 f0 = fb[(size_t)i0 * 64];
                uint2 f1 = fb[(size_t)i1 * 64];
                uint2 f2 = fb[(size_t)i2 * 64];
                uint2 f3 = fb[(size_t)i3 * 64];
                float4 A0 = *(const float4*)&alds[w][u + 0][0];
                float4 A1 = *(const float4*)&alds[w][u + 1][0];
                float4 A2 = *(const float4*)&alds[w][u + 2][0];
                float4 A3 = *(const float4*)&alds[w][u + 3][0];

                r0 = fmaf(A0.x, bf_lo(f0.x), r0); r1 = fmaf(A0.y, bf_hi(f0.x), r1);
                r2 = fmaf(A0.z, bf_lo(f0.y), r2); r3 = fmaf(A0.w, bf_hi(f0.y), r3);

                r0 = fmaf(A1.x, bf_lo(f1.x), r0); r1 = fmaf(A1.y, bf_hi(f1.x), r1);
                r2 = fmaf(A1.z, bf_lo(f1.y), r2); r3 = fmaf(A1.w, bf_hi(f1.y), r3);

                r0 = fmaf(A2.x, bf_lo(f2.x), r0); r1 = fmaf(A2.y, bf_hi(f2.x), r1);
                r2 = fmaf(A2.z, bf_lo(f2.y), r2); r3 = fmaf(A2.w, bf_hi(f2.y), r3);

                r0 = fmaf(A3.x, bf_lo(f3.x), r0); r1 = fmaf(A3.y, bf_hi(f3.x), r1);
                r2 = fmaf(A3.z, bf_lo(f3.y), r2); r3 = fmaf(A3.w, bf_hi(f3.y), r3);
            }
        }

        // denominators: reduce per-lane partial sums across the wave
        #pragma unroll
        for (int off = 1; off < 64; off <<= 1) {
            ss0 += __shfl_xor(ss0, off, 64);
            ss1 += __shfl_xor(ss1, off, 64);
            ss2 += __shfl_xor(ss2, off, 64);
            ss3 += __shfl_xor(ss3, off, 64);
        }
        float wk = weight[k];
        acc0 = fmaf(r0, wk * __builtin_amdgcn_rcpf(ss0), acc0);
        acc1 = fmaf(r1, wk * __builtin_amdgcn_rcpf(ss1), acc1);
        acc2 = fmaf(r2, wk * __builtin_amdgcn_rcpf(ss2), acc2);
        acc3 = fmaf(r3, wk * __builtin_amdgcn_rcpf(ss3), acc3);
    }

    float wb = weight[0] * gat_bias[e] + weight[1] * gat_bias[HD + e]
             + weight[2] * gat_bias[2 * HD + e];
    acc0 += wb; acc1 += wb; acc2 += wb; acc3 += wb;

    gat[((size_t)n * BT + btg4 * 4 + 0) * HD + e] = acc0;
    gat[((size_t)n * BT + btg4 * 4 + 1) * HD + e] = acc1;
    gat[((size_t)n * BT + btg4 * 4 + 2) * HD + e] = acc2;
    gat[((size_t)n * BT + btg4 * 4 + 3) * HD + e] = acc3;
}

// ---------------- Pass E: merge GEMV + leakyrelu + residual -----------------
__global__ __launch_bounds__(128) void merge_kernel(
    const float* __restrict__ gat,
    const float* __restrict__ merge_w, const float* __restrict__ merge_b,
    const float* __restrict__ x, float* __restrict__ out)
{
    int m = blockIdx.x >> 10;        // 0..5 (8-bt group)
    int n = blockIdx.x & 1023;
    int e = threadIdx.x;             // 0..127

    __shared__ float rows[8][HD];    // 4 KB
    #pragma unroll
    for (int i = 0; i < 8; ++i)
        rows[i][e] = gat[((size_t)n * BT + m * 8 + i) * HD + e];
    __syncthreads();

    #pragma unroll
    for (int pass = 0; pass < 4; ++pass) {
        int oi = pass * 128 + e;     // 512 outputs: 8 rows x 64 cols
        int rr = oi >> 6, dd = oi & 63;
        float mg = merge_b[dd];
        #pragma unroll
        for (int q = 0; q < HD; ++q) mg = fmaf(rows[rr][q], merge_w[q * DD + dd], mg);
        mg = mg > 0.f ? mg : mg * 0.01f;
        int bt = m * 8 + rr;
        int b = bt / TT, t = bt - b * TT;
        size_t oidx = (((size_t)b * NN + n) * TT + t) * DD + dd;
        out[oidx] = mg + x[oidx];
    }
}

extern "C" void kernel_launch(void* const* d_in, const int* in_sizes, int n_in,
                              void* d_out, int out_size, void* d_ws, size_t ws_size,
                              hipStream_t stream)
{
    const float* x        = (const float*)d_in[0];
    const float* fc_w     = (const float*)d_in[1];
    const float* attn_l   = (const float*)d_in[2];
    const float* attn_r   = (const float*)d_in[3];
    const float* gat_bias = (const float*)d_in[4];
    const float* weight   = (const float*)d_in[5];
    const float* merge_w  = (const float*)d_in[6];
    const float* merge_b  = (const float*)d_in[7];
    const int*   src_idx  = (const int*)d_in[8];
    const int*   dst_idx  = (const int*)d_in[9];
    float*       out      = (float*)d_out;

    char* p = (char*)d_ws;
    auto carve = [&](size_t bytes) { char* r = p; p += (bytes + 15) & ~size_t(15); return r; };
    uint2* featp   = (uint2*)carve(sizeof(uint2) * (size_t)24 * NODES * 64);   // 37.8 MB
    float* elp     = (float*)carve(sizeof(float) * (size_t)24 * NODES * 4);
    float* er      = (float*)carve(sizeof(float) * (size_t)KK * NN * BTH);
    float* gat     = (float*)carve(sizeof(float) * (size_t)NN * BT * HD);      // 25.2 MB
    float* alc     = (float*)carve(sizeof(float) * KK * HH * CC);
    float* arc     = (float*)carve(sizeof(float) * KK * HH * CC);
    int*   counts  = (int*)carve(sizeof(int) * KK * NN);
    int*   cursor  = (int*)carve(sizeof(int) * KK * NN);
    int4*  segs    = (int4*)carve(sizeof(int4) * NN);
    int*   csr_comb= (int*)carve(sizeof(int) * (CSR_CAP + 80));

    hipMemsetAsync(counts, 0, sizeof(int) * KK * NN, stream);

    aux_kernel<<<EDGE_BLOCKS + 1, 256, 0, stream>>>(
        dst_idx, counts, fc_w, attn_l, attn_r, alc, arc, featp, elp);

    feat_mfma_kernel<<<KK * NBLK, 256, 0, stream>>>(x, fc_w, featp);

    elr_kernel<<<NN, 128, 0, stream>>>(x, alc, arc, elp, er);

    scan_kernel<<<1, 1024, 0, stream>>>(counts, segs, cursor, csr_comb);
    scatter_kernel<<<EDGE_BLOCKS, 256, 0, stream>>>(src_idx, dst_idx, cursor, csr_comb);

    agg_kernel<<<24 * 256, 256, 0, stream>>>(
        featp, elp, er, segs, csr_comb, gat_bias, weight, gat);

    merge_kernel<<<NN * 6, 128, 0, stream>>>(gat, merge_w, merge_b, x, out);
}

// Round 12
// 145.491 us; speedup vs baseline: 1.9030x; 1.1558x over previous
//
#include <hip/hip_runtime.h>

#define NN   1024
#define TT   12
#define CC   64
#define DD   64
#define HH   2
#define KK   3
#define ETOT 17408           // E (16384) + N self loops
#define BT   48              // B*T
#define BTH  96              // B*T*H
#define HD   128             // H*D
#define NODES (KK * NN + 1)  // +1 sentinel pad node (feat=0, el=-inf)
#define PADN  (KK * NN)
#define CSR_CAP (KK * ETOT + 12 * NN)   // segments padded to x4 (= 64512)
#define LOG2E 1.44269504f
#define MT   128                         // feat GEMM M-tile
#define NBLK (NN * BT / MT)              // 384 M-tiles per k
#define EDGE_BLOCKS ((KK * ETOT + 255) / 256)   // 204

typedef __attribute__((ext_vector_type(8))) short s8v;    // 8 bf16
typedef __attribute__((ext_vector_type(4))) float f4v;    // 4 f32 acc

__device__ __forceinline__ float bf_lo(unsigned int u) {
    return __uint_as_float(u << 16);
}
__device__ __forceinline__ float bf_hi(unsigned int u) {
    return __uint_as_float(u & 0xFFFF0000u);
}
__device__ __forceinline__ unsigned short f2bf(float f) {
    unsigned int u = __float_as_uint(f);
    u += 0x7FFFu + ((u >> 16) & 1u);      // round-to-nearest-even
    return (unsigned short)(u >> 16);
}
__device__ __forceinline__ unsigned int pack2(float a, float b) {
    return (unsigned int)f2bf(a) | ((unsigned int)f2bf(b) << 16);
}

// ---------------- aux: count (blocks 0..203) + prep_alc + pad-init ----------
__global__ __launch_bounds__(256) void aux_kernel(
    const int* __restrict__ dst_idx, int* __restrict__ counts,
    const float* __restrict__ fc_w, const float* __restrict__ attn_l,
    const float* __restrict__ attn_r, float* __restrict__ alc, float* __restrict__ arc,
    uint2* __restrict__ featp, float* __restrict__ elp)
{
    int bid = blockIdx.x;
    int t = threadIdx.x;
    if (bid < EDGE_BLOCKS) {
        int tid = bid * 256 + t;
        if (tid < KK * ETOT) {
            int k = tid / ETOT;
            atomicAdd(&counts[k * NN + dst_idx[tid]], 1);
        }
    } else {
        for (int item = t; item < KK * HH * CC; item += 256) {   // prep_alc
            int kh = item >> 6, c = item & 63;
            int k = kh >> 1, h = kh & 1;
            float sl = 0.f, sr = 0.f;
            #pragma unroll
            for (int dd = 0; dd < 64; ++dd) {
                float wv = fc_w[k * CC * HD + c * HD + h * 64 + dd];
                sl = fmaf(wv, attn_l[k * HD + h * 64 + dd], sl);
                sr = fmaf(wv, attn_r[k * HD + h * 64 + dd], sr);
            }
            alc[item] = sl * LOG2E;
            arc[item] = sr * LOG2E;
        }
        for (int item = t; item < 24 * 64; item += 256)          // feat pad node
            featp[((size_t)(item >> 6) * NODES + PADN) * 64 + (item & 63)] = make_uint2(0u, 0u);
        for (int item = t; item < 24 * 4; item += 256)           // elp pad node
            elp[((size_t)(item >> 2) * NODES + PADN) * 4 + (item & 3)] = -1e30f;
    }
}

// ---------------- Pass A1: feat = x @ fc_w via bf16 MFMA --------------------
__global__ __launch_bounds__(256) void feat_mfma_kernel(
    const float* __restrict__ x,       // [B,N,T,C]
    const float* __restrict__ fc_w,    // [K,C,HD]
    uint2* __restrict__ featp)
{
    int k  = blockIdx.x / NBLK;
    int m0 = (blockIdx.x - k * NBLK) * MT;
    int t  = threadIdx.x;              // 0..255
    int w  = t >> 6, l = t & 63;

    __shared__ __align__(16) unsigned short As[128 * 64];  // x tile bf16 [row][c], swz
    __shared__ __align__(16) unsigned short Ws[128 * 64];  // W^T bf16 [e][c], swz

    #pragma unroll
    for (int rep = 0; rep < 4; ++rep) {
        int gid = t + 256 * rep;       // 0..1023
        int row = gid >> 3, g = gid & 7;
        int m = m0 + row;
        int n = m / BT, bt = m - n * BT;
        int b = bt / TT, tt2 = bt - b * TT;
        const float* xr = &x[(((size_t)b * NN + n) * TT + tt2) * CC + g * 8];
        float4 v0 = *(const float4*)xr;
        float4 v1 = *(const float4*)(xr + 4);
        uint4 pk = { pack2(v0.x, v0.y), pack2(v0.z, v0.w),
                     pack2(v1.x, v1.y), pack2(v1.z, v1.w) };
        *(uint4*)((char*)As + row * 128 + ((g ^ (row & 7)) << 4)) = pk;
    }
    #pragma unroll
    for (int rep = 0; rep < 4; ++rep) {
        int gid = t + 256 * rep;
        int e = gid & 127, g = gid >> 7;
        float v[8];
        #pragma unroll
        for (int jj = 0; jj < 8; ++jj)
            v[jj] = fc_w[(size_t)k * CC * HD + (g * 8 + jj) * HD + e];
        uint4 pk = { pack2(v[0], v[1]), pack2(v[2], v[3]),
                     pack2(v[4], v[5]), pack2(v[6], v[7]) };
        *(uint4*)((char*)Ws + e * 128 + ((g ^ (e & 7)) << 4)) = pk;
    }
    __syncthreads();

    int Mw = (w & 1) * 64;
    int Nw = (w >> 1) * 64;
    int rsel = l & 15, ksel = l >> 4;

    f4v acc[4][4];
    #pragma unroll
    for (int mi = 0; mi < 4; ++mi)
        #pragma unroll
        for (int nf = 0; nf < 4; ++nf)
            acc[mi][nf] = (f4v){0.f, 0.f, 0.f, 0.f};

    s8v af[4][2], bf[4][2];
    #pragma unroll
    for (int mi = 0; mi < 4; ++mi)
        #pragma unroll
        for (int ks = 0; ks < 2; ++ks) {
            int row = Mw + mi * 16 + rsel;
            int g = ks * 4 + ksel;
            af[mi][ks] = *(const s8v*)((const char*)As + row * 128 + ((g ^ (row & 7)) << 4));
        }
    #pragma unroll
    for (int nf = 0; nf < 4; ++nf)
        #pragma unroll
        for (int ks = 0; ks < 2; ++ks) {
            int e = Nw + nf * 16 + rsel;
            int g = ks * 4 + ksel;
            bf[nf][ks] = *(const s8v*)((const char*)Ws + e * 128 + ((g ^ (e & 7)) << 4));
        }

    #pragma unroll
    for (int mi = 0; mi < 4; ++mi)
        #pragma unroll
        for (int nf = 0; nf < 4; ++nf) {
            acc[mi][nf] = __builtin_amdgcn_mfma_f32_16x16x32_bf16(
                af[mi][0], bf[nf][0], acc[mi][nf], 0, 0, 0);
            acc[mi][nf] = __builtin_amdgcn_mfma_f32_16x16x32_bf16(
                af[mi][1], bf[nf][1], acc[mi][nf], 0, 0, 0);
        }

    int i0 = (l >> 4) * 4;
    #pragma unroll
    for (int mi = 0; mi < 4; ++mi) {
        int m = m0 + Mw + mi * 16 + i0;
        int n = m / BT, bt = m - n * BT;
        #pragma unroll
        for (int nf = 0; nf < 4; ++nf) {
            int e = Nw + nf * 16 + (l & 15);
            int h = e >> 6, d = e & 63;
            int s = (bt >> 2) * 2 + h;
            uint2 o = { pack2(acc[mi][nf][0], acc[mi][nf][1]),
                        pack2(acc[mi][nf][2], acc[mi][nf][3]) };
            featp[((size_t)s * NODES + k * NN + n) * 64 + d] = o;
        }
    }
}

// ---------------- Pass A2: el/er (tiny GEMV per n) ---------------------------
__global__ __launch_bounds__(128) void elr_kernel(
    const float* __restrict__ x, const float* __restrict__ alc,
    const float* __restrict__ arc, float* __restrict__ elp, float* __restrict__ er)
{
    int n = blockIdx.x;
    int e = threadIdx.x;               // 0..127
    __shared__ float x_lds[BT * CC];   // 12 KB
    __shared__ float cl[KK * HH * CC];
    __shared__ float cr[KK * HH * CC];

    for (int i = e; i < BT * CC; i += 128) {
        int bt = i >> 6, c = i & 63;
        int b = bt / TT, tt = bt - b * TT;
        x_lds[i] = x[(((size_t)b * NN + n) * TT + tt) * CC + c];
    }
    for (int i = e; i < KK * HH * CC; i += 128) { cl[i] = alc[i]; cr[i] = arc[i]; }
    __syncthreads();

    if (e < BTH) {
        int hh = e / BT, bt = e - hh * BT;
        #pragma unroll
        for (int k = 0; k < KK; ++k) {
            const float* alp = &cl[(k * HH + hh) * CC];
            const float* arp = &cr[(k * HH + hh) * CC];
            float sl = 0.f, sr = 0.f;
            #pragma unroll
            for (int cc = 0; cc < CC; ++cc) {
                int c = (cc + bt) & 63;
                float xv = x_lds[bt * CC + c];
                sl = fmaf(xv, alp[c], sl);
                sr = fmaf(xv, arp[c], sr);
            }
            int s = (bt >> 2) * 2 + hh;
            elp[((size_t)s * NODES + k * NN + n) * 4 + (bt & 3)] = sl;
            er[((size_t)(k * NN + n)) * BTH + e] = sr;
        }
    }
}

// ---------------- CSR build (per-(k,n) segments, padded to 4) ---------------
__global__ __launch_bounds__(1024) void scan_kernel(
    const int* __restrict__ counts,
    int4* __restrict__ segs, int* __restrict__ cursor, int* __restrict__ csr_comb)
{
    int n = threadIdx.x;
    int c0 = counts[n], c1 = counts[NN + n], c2 = counts[2 * NN + n];
    int p0 = (c0 + 3) & ~3, p1 = (c1 + 3) & ~3, p2 = (c2 + 3) & ~3;
    int tot = p0 + p1 + p2;
    __shared__ int buf[NN];
    buf[n] = tot;
    __syncthreads();
    for (int off = 1; off < NN; off <<= 1) {
        int v = (n >= off) ? buf[n - off] : 0;
        __syncthreads();
        buf[n] += v;
        __syncthreads();
    }
    int excl = buf[n] - tot;
    int4 sg;
    sg.x = excl; sg.y = excl + p0; sg.z = excl + p0 + p1; sg.w = excl + tot;
    segs[n] = sg;
    cursor[n] = sg.x;
    cursor[NN + n] = sg.y;
    cursor[2 * NN + n] = sg.z;
    for (int j = sg.x + c0; j < sg.y; ++j) csr_comb[j] = PADN;
    for (int j = sg.y + c1; j < sg.z; ++j) csr_comb[j] = PADN;
    for (int j = sg.z + c2; j < sg.w; ++j) csr_comb[j] = PADN;
}

__global__ void scatter_kernel(const int* __restrict__ src_idx,
                               const int* __restrict__ dst_idx,
                               int* __restrict__ cursor, int* __restrict__ csr_comb)
{
    int tid = blockIdx.x * blockDim.x + threadIdx.x;
    if (tid < KK * ETOT) {
        int k = tid / ETOT;
        int pos = atomicAdd(&cursor[k * NN + dst_idx[tid]], 1);
        csr_comb[pos] = k * NN + src_idx[tid];
    }
}

// ---------------- Pass C: prescaled alpha, slice-pinned ---------------------
// alpha[s][j][bt] = exp2(lrelu(el+er)) * weight[k] / denom  (csr order)
// grid 1536: xcd=bid&7, q=bid>>3 (0..191): sl=q/64, nb=q%64; s=xcd+8*sl
// block 256 = 4 waves; wave w covers n = nb*16 + w*4 + (0..3), all 3 k.
__global__ __launch_bounds__(256) void attn_kernel(
    const float* __restrict__ elp, const float* __restrict__ er,
    const int4* __restrict__ segs, const int* __restrict__ csr_comb,
    const float* __restrict__ weight, float* __restrict__ alpha)
{
    int bid = blockIdx.x;
    int xcd = bid & 7, q = bid >> 3;
    int sl = q / 64, nb = q - sl * 64;
    int s = xcd + 8 * sl;
    int w = threadIdx.x >> 6, l = threadIdx.x & 63;
    int btg4 = s >> 1, h = s & 1;
    int joff = l >> 2, bt = l & 3;     // lane covers (edge j0+joff, bt)
    const float* ep = elp + (size_t)s * NODES * 4;
    float* ap = alpha + (size_t)s * CSR_CAP * 4;

    for (int ni = 0; ni < 4; ++ni) {
        int n = nb * 16 + w * 4 + ni;
        int4 sg = segs[n];
        #pragma unroll
        for (int k = 0; k < KK; ++k) {
            int jb = (k == 0) ? sg.x : (k == 1) ? sg.y : sg.z;
            int je = (k == 0) ? sg.y : (k == 1) ? sg.z : sg.w;
            float erv = er[((size_t)(k * NN + n)) * BTH + h * BT + btg4 * 4 + bt];

            float ss = 0.f;
            for (int j0 = jb; j0 < je; j0 += 16) {
                int jj = j0 + joff;
                float a = 0.f;
                if (jj < je) {
                    int idx = csr_comb[jj];
                    float ev = ep[idx * 4 + bt] + erv;
                    ev = fmaxf(ev, ev * 0.2f);
                    a = __builtin_amdgcn_exp2f(ev);
                }
                ss += a;
            }
            #pragma unroll
            for (int off = 4; off < 64; off <<= 1)
                ss += __shfl_xor(ss, off, 64);
            float scale = weight[k] * __builtin_amdgcn_rcpf(ss);

            for (int j0 = jb; j0 < je; j0 += 16) {
                int jj = j0 + joff;
                if (jj < je) {
                    int idx = csr_comb[jj];
                    float ev = ep[idx * 4 + bt] + erv;
                    ev = fmaxf(ev, ev * 0.2f);
                    ap[(size_t)jj * 4 + bt] = __builtin_amdgcn_exp2f(ev) * scale;
                }
            }
        }
    }
}

// ---------------- Pass D: weighted gather-sum, slice-pinned to XCDs ---------
__global__ __launch_bounds__(256) void agg_kernel(
    const uint2* __restrict__ featp,
    const float* __restrict__ alpha,
    const int4* __restrict__ segs, const int* __restrict__ csr_comb,
    const float* __restrict__ gat_bias, const float* __restrict__ weight,
    unsigned short* __restrict__ gatb)   // [n*BT+bt][HD] bf16
{
    int j = ((int)blockIdx.x >> 3) + 768 * ((int)blockIdx.x & 7);
    int s = j >> 8;
    int g = j & 255;
    int w = threadIdx.x >> 6;
    int d = threadIdx.x & 63;
    int n = g * 4 + w;
    int btg4 = s >> 1, h = s & 1;
    int e = h * 64 + d;

    const uint2* fb = featp + (size_t)s * NODES * 64 + d;
    const float* ap = alpha + (size_t)s * CSR_CAP * 4;
    int4 sg = segs[n];
    int jb = __builtin_amdgcn_readfirstlane(sg.x);
    int je = __builtin_amdgcn_readfirstlane(sg.w);

    float r0 = 0.f, r1 = 0.f, r2 = 0.f, r3 = 0.f;

    #pragma unroll 2
    for (int jj = jb; jj < je; jj += 4) {
        int4 i4 = *(const int4*)&csr_comb[jj];
        int i0 = __builtin_amdgcn_readfirstlane(i4.x);
        int i1 = __builtin_amdgcn_readfirstlane(i4.y);
        int i2 = __builtin_amdgcn_readfirstlane(i4.z);
        int i3 = __builtin_amdgcn_readfirstlane(i4.w);
        uint2 f0 = fb[(size_t)i0 * 64];
        uint2 f1 = fb[(size_t)i1 * 64];
        uint2 f2 = fb[(size_t)i2 * 64];
        uint2 f3 = fb[(size_t)i3 * 64];
        float4 A0 = *(const float4*)&ap[(size_t)(jj + 0) * 4];
        float4 A1 = *(const float4*)&ap[(size_t)(jj + 1) * 4];
        float4 A2 = *(const float4*)&ap[(size_t)(jj + 2) * 4];
        float4 A3 = *(const float4*)&ap[(size_t)(jj + 3) * 4];

        r0 = fmaf(A0.x, bf_lo(f0.x), r0); r1 = fmaf(A0.y, bf_hi(f0.x), r1);
        r2 = fmaf(A0.z, bf_lo(f0.y), r2); r3 = fmaf(A0.w, bf_hi(f0.y), r3);

        r0 = fmaf(A1.x, bf_lo(f1.x), r0); r1 = fmaf(A1.y, bf_hi(f1.x), r1);
        r2 = fmaf(A1.z, bf_lo(f1.y), r2); r3 = fmaf(A1.w, bf_hi(f1.y), r3);

        r0 = fmaf(A2.x, bf_lo(f2.x), r0); r1 = fmaf(A2.y, bf_hi(f2.x), r1);
        r2 = fmaf(A2.z, bf_lo(f2.y), r2); r3 = fmaf(A2.w, bf_hi(f2.y), r3);

        r0 = fmaf(A3.x, bf_lo(f3.x), r0); r1 = fmaf(A3.y, bf_hi(f3.x), r1);
        r2 = fmaf(A3.z, bf_lo(f3.y), r2); r3 = fmaf(A3.w, bf_hi(f3.y), r3);
    }

    float wb = weight[0] * gat_bias[e] + weight[1] * gat_bias[HD + e]
             + weight[2] * gat_bias[2 * HD + e];
    r0 += wb; r1 += wb; r2 += wb; r3 += wb;

    size_t row = (size_t)n * BT + btg4 * 4;
    gatb[(row + 0) * HD + e] = f2bf(r0);
    gatb[(row + 1) * HD + e] = f2bf(r1);
    gatb[(row + 2) * HD + e] = f2bf(r2);
    gatb[(row + 3) * HD + e] = f2bf(r3);
}

// ---------------- Pass E: merge via bf16 MFMA + leakyrelu + residual --------
// out[M=49152, 64] = lrelu(gatb[M,128] @ merge_w[128,64] + b) + x
__global__ __launch_bounds__(256) void merge_mfma_kernel(
    const unsigned short* __restrict__ gatb,
    const float* __restrict__ merge_w, const float* __restrict__ merge_b,
    const float* __restrict__ x, float* __restrict__ out)
{
    int m0 = blockIdx.x * 128;
    int t = threadIdx.x, w = t >> 6, l = t & 63;

    __shared__ __align__(16) unsigned short As[128 * 128]; // 32 KB, swz
    __shared__ __align__(16) unsigned short Bs[64 * 128];  // 16 KB, swz

    #pragma unroll
    for (int rep = 0; rep < 8; ++rep) {
        int gid = t + 256 * rep;       // 0..2047
        int row = gid >> 4, gg = gid & 15;
        uint4 v = *(const uint4*)((const char*)gatb + ((size_t)(m0 + row)) * 256 + gg * 16);
        *(uint4*)((char*)As + row * 256 + ((gg ^ (row & 15)) << 4)) = v;
    }
    #pragma unroll
    for (int rep = 0; rep < 4; ++rep) {
        int gid = t + 256 * rep;       // 0..1023
        int col = gid >> 4, gg = gid & 15;
        float v[8];
        #pragma unroll
        for (int jj = 0; jj < 8; ++jj)
            v[jj] = merge_w[(gg * 8 + jj) * DD + col];
        uint4 pk = { pack2(v[0], v[1]), pack2(v[2], v[3]),
                     pack2(v[4], v[5]), pack2(v[6], v[7]) };
        *(uint4*)((char*)Bs + col * 256 + ((gg ^ (col & 15)) << 4)) = pk;
    }
    __syncthreads();

    int Mw = (w & 1) * 64, Nw = (w >> 1) * 32;
    int rsel = l & 15, ksel = l >> 4;

    f4v acc[4][2];
    #pragma unroll
    for (int mi = 0; mi < 4; ++mi)
        #pragma unroll
        for (int nf = 0; nf < 2; ++nf)
            acc[mi][nf] = (f4v){0.f, 0.f, 0.f, 0.f};

    s8v af[4][4], bfr[2][4];
    #pragma unroll
    for (int mi = 0; mi < 4; ++mi)
        #pragma unroll
        for (int ks = 0; ks < 4; ++ks) {
            int row = Mw + mi * 16 + rsel;
            int g2 = ks * 4 + ksel;
            af[mi][ks] = *(const s8v*)((const char*)As + row * 256 + ((g2 ^ (row & 15)) << 4));
        }
    #pragma unroll
    for (int nf = 0; nf < 2; ++nf)
        #pragma unroll
        for (int ks = 0; ks < 4; ++ks) {
            int col = Nw + nf * 16 + rsel;
            int g2 = ks * 4 + ksel;
            bfr[nf][ks] = *(const s8v*)((const char*)Bs + col * 256 + ((g2 ^ (col & 15)) << 4));
        }

    #pragma unroll
    for (int mi = 0; mi < 4; ++mi)
        #pragma unroll
        for (int nf = 0; nf < 2; ++nf)
            #pragma unroll
            for (int ks = 0; ks < 4; ++ks)
                acc[mi][nf] = __builtin_amdgcn_mfma_f32_16x16x32_bf16(
                    af[mi][ks], bfr[nf][ks], acc[mi][nf], 0, 0, 0);

    int i0 = (l >> 4) * 4;
    #pragma unroll
    for (int mi = 0; mi < 4; ++mi) {
        int m = m0 + Mw + mi * 16 + i0;          // 4 rows, same n/b (4 | 12 | 48)
        int n = m / BT, btb = m - n * BT;
        int b = btb / TT, t0 = btb - b * TT;
        #pragma unroll
        for (int nf = 0; nf < 2; ++nf) {
            int dd = Nw + nf * 16 + (l & 15);
            float mb = merge_b[dd];
            #pragma unroll
            for (int reg = 0; reg < 4; ++reg) {
                float mg = acc[mi][nf][reg] + mb;
                mg = mg > 0.f ? mg : mg * 0.01f;
                size_t oidx = (((size_t)b * NN + n) * TT + t0 + reg) * DD + dd;
                out[oidx] = mg + x[oidx];
            }
        }
    }
}

extern "C" void kernel_launch(void* const* d_in, const int* in_sizes, int n_in,
                              void* d_out, int out_size, void* d_ws, size_t ws_size,
                              hipStream_t stream)
{
    const float* x        = (const float*)d_in[0];
    const float* fc_w     = (const float*)d_in[1];
    const float* attn_l   = (const float*)d_in[2];
    const float* attn_r   = (const float*)d_in[3];
    const float* gat_bias = (const float*)d_in[4];
    const float* weight   = (const float*)d_in[5];
    const float* merge_w  = (const float*)d_in[6];
    const float* merge_b  = (const float*)d_in[7];
    const int*   src_idx  = (const int*)d_in[8];
    const int*   dst_idx  = (const int*)d_in[9];
    float*       out      = (float*)d_out;

    char* p = (char*)d_ws;
    auto carve = [&](size_t bytes) { char* r = p; p += (bytes + 15) & ~size_t(15); return r; };
    uint2* featp   = (uint2*)carve(sizeof(uint2) * (size_t)24 * NODES * 64);      // 37.8 MB
    float* alpha   = (float*)carve(sizeof(float) * (size_t)24 * CSR_CAP * 4);     // 24.8 MB
    unsigned short* gatb = (unsigned short*)carve(sizeof(unsigned short) * (size_t)NN * BT * HD); // 12.6 MB
    float* elp     = (float*)carve(sizeof(float) * (size_t)24 * NODES * 4);
    float* er      = (float*)carve(sizeof(float) * (size_t)KK * NN * BTH);
    float* alc     = (float*)carve(sizeof(float) * KK * HH * CC);
    float* arc     = (float*)carve(sizeof(float) * KK * HH * CC);
    int*   counts  = (int*)carve(sizeof(int) * KK * NN);
    int*   cursor  = (int*)carve(sizeof(int) * KK * NN);
    int4*  segs    = (int4*)carve(sizeof(int4) * NN);
    int*   csr_comb= (int*)carve(sizeof(int) * (CSR_CAP + 80));

    hipMemsetAsync(counts, 0, sizeof(int) * KK * NN, stream);

    aux_kernel<<<EDGE_BLOCKS + 1, 256, 0, stream>>>(
        dst_idx, counts, fc_w, attn_l, attn_r, alc, arc, featp, elp);

    feat_mfma_kernel<<<KK * NBLK, 256, 0, stream>>>(x, fc_w, featp);

    elr_kernel<<<NN, 128, 0, stream>>>(x, alc, arc, elp, er);

    scan_kernel<<<1, 1024, 0, stream>>>(counts, segs, cursor, csr_comb);
    scatter_kernel<<<EDGE_BLOCKS, 256, 0, stream>>>(src_idx, dst_idx, cursor, csr_comb);

    attn_kernel<<<1536, 256, 0, stream>>>(elp, er, segs, csr_comb, weight, alpha);

    agg_kernel<<<24 * 256, 256, 0, stream>>>(
        featp, alpha, segs, csr_comb, gat_bias, weight, gatb);

    merge_mfma_kernel<<<NN * BT / 128, 256, 0, stream>>>(gatb, merge_w, merge_b, x, out);
}

// Round 13
// 143.919 us; speedup vs baseline: 1.9238x; 1.0109x over previous
//
#include <hip/hip_runtime.h>

#define NN   1024
#define TT   12
#define CC   64
#define DD   64
#define HH   2
#define KK   3
#define ETOT 17408           // E (16384) + N self loops
#define BT   48              // B*T
#define BTH  96              // B*T*H
#define HD   128             // H*D
#define NODES (KK * NN + 1)  // +1 sentinel pad node (feat=0, el=-inf)
#define PADN  (KK * NN)
#define CSR_CAP (KK * ETOT + 12 * NN)   // segments padded to x4 (= 64512)
#define LOG2E 1.44269504f
#define MT   128                         // feat GEMM M-tile
#define NBLK (NN * BT / MT)              // 384 M-tiles per k
#define EDGE_BLOCKS ((KK * ETOT + 255) / 256)   // 204

typedef __attribute__((ext_vector_type(8))) short s8v;    // 8 bf16
typedef __attribute__((ext_vector_type(4))) float f4v;    // 4 f32 acc

__device__ __forceinline__ float bf_lo(unsigned int u) {
    return __uint_as_float(u << 16);
}
__device__ __forceinline__ float bf_hi(unsigned int u) {
    return __uint_as_float(u & 0xFFFF0000u);
}
__device__ __forceinline__ unsigned short f2bf(float f) {
    unsigned int u = __float_as_uint(f);
    u += 0x7FFFu + ((u >> 16) & 1u);      // round-to-nearest-even
    return (unsigned short)(u >> 16);
}
__device__ __forceinline__ unsigned int pack2(float a, float b) {
    return (unsigned int)f2bf(a) | ((unsigned int)f2bf(b) << 16);
}

// ---------------- aux: count (blocks 0..203) + prep_alc + pad-init ----------
__global__ __launch_bounds__(256) void aux_kernel(
    const int* __restrict__ dst_idx, int* __restrict__ counts,
    const float* __restrict__ fc_w, const float* __restrict__ attn_l,
    const float* __restrict__ attn_r, float* __restrict__ alc, float* __restrict__ arc,
    uint2* __restrict__ featp, float* __restrict__ elp)
{
    int bid = blockIdx.x;
    int t = threadIdx.x;
    if (bid < EDGE_BLOCKS) {
        int tid = bid * 256 + t;
        if (tid < KK * ETOT) {
            int k = tid / ETOT;
            atomicAdd(&counts[k * NN + dst_idx[tid]], 1);
        }
    } else {
        for (int item = t; item < KK * HH * CC; item += 256) {   // prep_alc
            int kh = item >> 6, c = item & 63;
            int k = kh >> 1, h = kh & 1;
            float sl = 0.f, sr = 0.f;
            #pragma unroll
            for (int dd = 0; dd < 64; ++dd) {
                float wv = fc_w[k * CC * HD + c * HD + h * 64 + dd];
                sl = fmaf(wv, attn_l[k * HD + h * 64 + dd], sl);
                sr = fmaf(wv, attn_r[k * HD + h * 64 + dd], sr);
            }
            alc[item] = sl * LOG2E;
            arc[item] = sr * LOG2E;
        }
        for (int item = t; item < 24 * 64; item += 256)          // feat pad node
            featp[((size_t)(item >> 6) * NODES + PADN) * 64 + (item & 63)] = make_uint2(0u, 0u);
        for (int item = t; item < 24 * 4; item += 256)           // elp pad node
            elp[((size_t)(item >> 2) * NODES + PADN) * 4 + (item & 3)] = -1e30f;
    }
}

// ---------------- Pass A1: feat = x @ fc_w via bf16 MFMA --------------------
__global__ __launch_bounds__(256) void feat_mfma_kernel(
    const float* __restrict__ x,       // [B,N,T,C]
    const float* __restrict__ fc_w,    // [K,C,HD]
    uint2* __restrict__ featp)
{
    int k  = blockIdx.x / NBLK;
    int m0 = (blockIdx.x - k * NBLK) * MT;
    int t  = threadIdx.x;              // 0..255
    int w  = t >> 6, l = t & 63;

    __shared__ __align__(16) unsigned short As[128 * 64];  // x tile bf16 [row][c], swz
    __shared__ __align__(16) unsigned short Ws[128 * 64];  // W^T bf16 [e][c], swz

    #pragma unroll
    for (int rep = 0; rep < 4; ++rep) {
        int gid = t + 256 * rep;       // 0..1023
        int row = gid >> 3, g = gid & 7;
        int m = m0 + row;
        int n = m / BT, bt = m - n * BT;
        int b = bt / TT, tt2 = bt - b * TT;
        const float* xr = &x[(((size_t)b * NN + n) * TT + tt2) * CC + g * 8];
        float4 v0 = *(const float4*)xr;
        float4 v1 = *(const float4*)(xr + 4);
        uint4 pk = { pack2(v0.x, v0.y), pack2(v0.z, v0.w),
                     pack2(v1.x, v1.y), pack2(v1.z, v1.w) };
        *(uint4*)((char*)As + row * 128 + ((g ^ (row & 7)) << 4)) = pk;
    }
    #pragma unroll
    for (int rep = 0; rep < 4; ++rep) {
        int gid = t + 256 * rep;
        int e = gid & 127, g = gid >> 7;
        float v[8];
        #pragma unroll
        for (int jj = 0; jj < 8; ++jj)
            v[jj] = fc_w[(size_t)k * CC * HD + (g * 8 + jj) * HD + e];
        uint4 pk = { pack2(v[0], v[1]), pack2(v[2], v[3]),
                     pack2(v[4], v[5]), pack2(v[6], v[7]) };
        *(uint4*)((char*)Ws + e * 128 + ((g ^ (e & 7)) << 4)) = pk;
    }
    __syncthreads();

    int Mw = (w & 1) * 64;
    int Nw = (w >> 1) * 64;
    int rsel = l & 15, ksel = l >> 4;

    f4v acc[4][4];
    #pragma unroll
    for (int mi = 0; mi < 4; ++mi)
        #pragma unroll
        for (int nf = 0; nf < 4; ++nf)
            acc[mi][nf] = (f4v){0.f, 0.f, 0.f, 0.f};

    s8v af[4][2], bf[4][2];
    #pragma unroll
    for (int mi = 0; mi < 4; ++mi)
        #pragma unroll
        for (int ks = 0; ks < 2; ++ks) {
            int row = Mw + mi * 16 + rsel;
            int g = ks * 4 + ksel;
            af[mi][ks] = *(const s8v*)((const char*)As + row * 128 + ((g ^ (row & 7)) << 4));
        }
    #pragma unroll
    for (int nf = 0; nf < 4; ++nf)
        #pragma unroll
        for (int ks = 0; ks < 2; ++ks) {
            int e = Nw + nf * 16 + rsel;
            int g = ks * 4 + ksel;
            bf[nf][ks] = *(const s8v*)((const char*)Ws + e * 128 + ((g ^ (e & 7)) << 4));
        }

    #pragma unroll
    for (int mi = 0; mi < 4; ++mi)
        #pragma unroll
        for (int nf = 0; nf < 4; ++nf) {
            acc[mi][nf] = __builtin_amdgcn_mfma_f32_16x16x32_bf16(
                af[mi][0], bf[nf][0], acc[mi][nf], 0, 0, 0);
            acc[mi][nf] = __builtin_amdgcn_mfma_f32_16x16x32_bf16(
                af[mi][1], bf[nf][1], acc[mi][nf], 0, 0, 0);
        }

    int i0 = (l >> 4) * 4;
    #pragma unroll
    for (int mi = 0; mi < 4; ++mi) {
        int m = m0 + Mw + mi * 16 + i0;
        int n = m / BT, bt = m - n * BT;
        #pragma unroll
        for (int nf = 0; nf < 4; ++nf) {
            int e = Nw + nf * 16 + (l & 15);
            int h = e >> 6, d = e & 63;
            int s = (bt >> 2) * 2 + h;
            uint2 o = { pack2(acc[mi][nf][0], acc[mi][nf][1]),
                        pack2(acc[mi][nf][2], acc[mi][nf][3]) };
            featp[((size_t)s * NODES + k * NN + n) * 64 + d] = o;
        }
    }
}

// ---------------- Pass A2: el/er (tiny GEMV per n) ---------------------------
__global__ __launch_bounds__(128) void elr_kernel(
    const float* __restrict__ x, const float* __restrict__ alc,
    const float* __restrict__ arc, float* __restrict__ elp, float* __restrict__ er)
{
    int n = blockIdx.x;
    int e = threadIdx.x;               // 0..127
    __shared__ float x_lds[BT * CC];   // 12 KB
    __shared__ float cl[KK * HH * CC];
    __shared__ float cr[KK * HH * CC];

    for (int i = e; i < BT * CC; i += 128) {
        int bt = i >> 6, c = i & 63;
        int b = bt / TT, tt = bt - b * TT;
        x_lds[i] = x[(((size_t)b * NN + n) * TT + tt) * CC + c];
    }
    for (int i = e; i < KK * HH * CC; i += 128) { cl[i] = alc[i]; cr[i] = arc[i]; }
    __syncthreads();

    if (e < BTH) {
        int hh = e / BT, bt = e - hh * BT;
        #pragma unroll
        for (int k = 0; k < KK; ++k) {
            const float* alp = &cl[(k * HH + hh) * CC];
            const float* arp = &cr[(k * HH + hh) * CC];
            float sl = 0.f, sr = 0.f;
            #pragma unroll
            for (int cc = 0; cc < CC; ++cc) {
                int c = (cc + bt) & 63;
                float xv = x_lds[bt * CC + c];
                sl = fmaf(xv, alp[c], sl);
                sr = fmaf(xv, arp[c], sr);
            }
            int s = (bt >> 2) * 2 + hh;
            elp[((size_t)s * NODES + k * NN + n) * 4 + (bt & 3)] = sl;
            er[((size_t)(k * NN + n)) * BTH + e] = sr;
        }
    }
}

// ---------------- CSR build (per-(k,n) segments, padded to 4) ---------------
__global__ __launch_bounds__(1024) void scan_kernel(
    const int* __restrict__ counts,
    int4* __restrict__ segs, int* __restrict__ cursor, int* __restrict__ csr_comb)
{
    int n = threadIdx.x;
    int c0 = counts[n], c1 = counts[NN + n], c2 = counts[2 * NN + n];
    int p0 = (c0 + 3) & ~3, p1 = (c1 + 3) & ~3, p2 = (c2 + 3) & ~3;
    int tot = p0 + p1 + p2;
    __shared__ int buf[NN];
    buf[n] = tot;
    __syncthreads();
    for (int off = 1; off < NN; off <<= 1) {
        int v = (n >= off) ? buf[n - off] : 0;
        __syncthreads();
        buf[n] += v;
        __syncthreads();
    }
    int excl = buf[n] - tot;
    int4 sg;
    sg.x = excl; sg.y = excl + p0; sg.z = excl + p0 + p1; sg.w = excl + tot;
    segs[n] = sg;
    cursor[n] = sg.x;
    cursor[NN + n] = sg.y;
    cursor[2 * NN + n] = sg.z;
    for (int j = sg.x + c0; j < sg.y; ++j) csr_comb[j] = PADN;
    for (int j = sg.y + c1; j < sg.z; ++j) csr_comb[j] = PADN;
    for (int j = sg.z + c2; j < sg.w; ++j) csr_comb[j] = PADN;
}

__global__ void scatter_kernel(const int* __restrict__ src_idx,
                               const int* __restrict__ dst_idx,
                               int* __restrict__ cursor, int* __restrict__ csr_comb)
{
    int tid = blockIdx.x * blockDim.x + threadIdx.x;
    if (tid < KK * ETOT) {
        int k = tid / ETOT;
        int pos = atomicAdd(&cursor[k * NN + dst_idx[tid]], 1);
        csr_comb[pos] = k * NN + src_idx[tid];
    }
}

// ---------------- Pass C: prescaled alpha, slice-pinned ---------------------
__global__ __launch_bounds__(256) void attn_kernel(
    const float* __restrict__ elp, const float* __restrict__ er,
    const int4* __restrict__ segs, const int* __restrict__ csr_comb,
    const float* __restrict__ weight, float* __restrict__ alpha)
{
    int bid = blockIdx.x;
    int xcd = bid & 7, q = bid >> 3;
    int sl = q / 64, nb = q - sl * 64;
    int s = xcd + 8 * sl;
    int w = threadIdx.x >> 6, l = threadIdx.x & 63;
    int btg4 = s >> 1, h = s & 1;
    int joff = l >> 2, bt = l & 3;     // lane covers (edge j0+joff, bt)
    const float* ep = elp + (size_t)s * NODES * 4;
    float* ap = alpha + (size_t)s * CSR_CAP * 4;

    for (int ni = 0; ni < 4; ++ni) {
        int n = nb * 16 + w * 4 + ni;
        int4 sg = segs[n];
        #pragma unroll
        for (int k = 0; k < KK; ++k) {
            int jb = (k == 0) ? sg.x : (k == 1) ? sg.y : sg.z;
            int je = (k == 0) ? sg.y : (k == 1) ? sg.z : sg.w;
            float erv = er[((size_t)(k * NN + n)) * BTH + h * BT + btg4 * 4 + bt];

            float ss = 0.f;
            for (int j0 = jb; j0 < je; j0 += 16) {
                int jj = j0 + joff;
                float a = 0.f;
                if (jj < je) {
                    int idx = csr_comb[jj];
                    float ev = ep[idx * 4 + bt] + erv;
                    ev = fmaxf(ev, ev * 0.2f);
                    a = __builtin_amdgcn_exp2f(ev);
                }
                ss += a;
            }
            #pragma unroll
            for (int off = 4; off < 64; off <<= 1)
                ss += __shfl_xor(ss, off, 64);
            float scale = weight[k] * __builtin_amdgcn_rcpf(ss);

            for (int j0 = jb; j0 < je; j0 += 16) {
                int jj = j0 + joff;
                if (jj < je) {
                    int idx = csr_comb[jj];
                    float ev = ep[idx * 4 + bt] + erv;
                    ev = fmaxf(ev, ev * 0.2f);
                    ap[(size_t)jj * 4 + bt] = __builtin_amdgcn_exp2f(ev) * scale;
                }
            }
        }
    }
}

// ---------------- Pass D: weighted gather-sum, 8-deep pipeline --------------
#define EDGE_FMA8(F, A)                                        \
    r0 = fmaf((A).x, bf_lo((F).x), r0);                        \
    r1 = fmaf((A).y, bf_hi((F).x), r1);                        \
    r2 = fmaf((A).z, bf_lo((F).y), r2);                        \
    r3 = fmaf((A).w, bf_hi((F).y), r3);

__global__ __launch_bounds__(256) void agg_kernel(
    const uint2* __restrict__ featp,
    const float* __restrict__ alpha,
    const int4* __restrict__ segs, const int* __restrict__ csr_comb,
    const float* __restrict__ gat_bias, const float* __restrict__ weight,
    unsigned short* __restrict__ gatb)   // [n*BT+bt][HD] bf16
{
    int j = ((int)blockIdx.x >> 3) + 768 * ((int)blockIdx.x & 7);
    int s = j >> 8;
    int g = j & 255;
    int w = threadIdx.x >> 6;
    int d = threadIdx.x & 63;
    int n = g * 4 + w;
    int btg4 = s >> 1, h = s & 1;
    int e = h * 64 + d;

    const uint2* fb = featp + (size_t)s * NODES * 64 + d;
    const float* ap = alpha + (size_t)s * CSR_CAP * 4;
    int4 sg = segs[n];
    int jb = __builtin_amdgcn_readfirstlane(sg.x);
    int je = __builtin_amdgcn_readfirstlane(sg.w);

    float r0 = 0.f, r1 = 0.f, r2 = 0.f, r3 = 0.f;

    int jj = jb;
    for (; jj + 8 <= je; jj += 8) {
        int4 ia = *(const int4*)&csr_comb[jj];
        int4 ib = *(const int4*)&csr_comb[jj + 4];
        int i0 = __builtin_amdgcn_readfirstlane(ia.x);
        int i1 = __builtin_amdgcn_readfirstlane(ia.y);
        int i2 = __builtin_amdgcn_readfirstlane(ia.z);
        int i3 = __builtin_amdgcn_readfirstlane(ia.w);
        int i4 = __builtin_amdgcn_readfirstlane(ib.x);
        int i5 = __builtin_amdgcn_readfirstlane(ib.y);
        int i6 = __builtin_amdgcn_readfirstlane(ib.z);
        int i7 = __builtin_amdgcn_readfirstlane(ib.w);
        uint2 f0 = fb[(size_t)i0 * 64];
        uint2 f1 = fb[(size_t)i1 * 64];
        uint2 f2 = fb[(size_t)i2 * 64];
        uint2 f3 = fb[(size_t)i3 * 64];
        uint2 f4 = fb[(size_t)i4 * 64];
        uint2 f5 = fb[(size_t)i5 * 64];
        uint2 f6 = fb[(size_t)i6 * 64];
        uint2 f7 = fb[(size_t)i7 * 64];
        float4 A0 = *(const float4*)&ap[(size_t)(jj + 0) * 4];
        float4 A1 = *(const float4*)&ap[(size_t)(jj + 1) * 4];
        float4 A2 = *(const float4*)&ap[(size_t)(jj + 2) * 4];
        float4 A3 = *(const float4*)&ap[(size_t)(jj + 3) * 4];
        float4 A4 = *(const float4*)&ap[(size_t)(jj + 4) * 4];
        float4 A5 = *(const float4*)&ap[(size_t)(jj + 5) * 4];
        float4 A6 = *(const float4*)&ap[(size_t)(jj + 6) * 4];
        float4 A7 = *(const float4*)&ap[(size_t)(jj + 7) * 4];

        EDGE_FMA8(f0, A0); EDGE_FMA8(f1, A1);
        EDGE_FMA8(f2, A2); EDGE_FMA8(f3, A3);
        EDGE_FMA8(f4, A4); EDGE_FMA8(f5, A5);
        EDGE_FMA8(f6, A6); EDGE_FMA8(f7, A7);
    }
    if (jj < je) {                     // one 4-wide tail (run is x4-aligned)
        int4 ia = *(const int4*)&csr_comb[jj];
        int i0 = __builtin_amdgcn_readfirstlane(ia.x);
        int i1 = __builtin_amdgcn_readfirstlane(ia.y);
        int i2 = __builtin_amdgcn_readfirstlane(ia.z);
        int i3 = __builtin_amdgcn_readfirstlane(ia.w);
        uint2 f0 = fb[(size_t)i0 * 64];
        uint2 f1 = fb[(size_t)i1 * 64];
        uint2 f2 = fb[(size_t)i2 * 64];
        uint2 f3 = fb[(size_t)i3 * 64];
        float4 A0 = *(const float4*)&ap[(size_t)(jj + 0) * 4];
        float4 A1 = *(const float4*)&ap[(size_t)(jj + 1) * 4];
        float4 A2 = *(const float4*)&ap[(size_t)(jj + 2) * 4];
        float4 A3 = *(const float4*)&ap[(size_t)(jj + 3) * 4];
        EDGE_FMA8(f0, A0); EDGE_FMA8(f1, A1);
        EDGE_FMA8(f2, A2); EDGE_FMA8(f3, A3);
    }

    float wb = weight[0] * gat_bias[e] + weight[1] * gat_bias[HD + e]
             + weight[2] * gat_bias[2 * HD + e];
    r0 += wb; r1 += wb; r2 += wb; r3 += wb;

    size_t row = (size_t)n * BT + btg4 * 4;
    gatb[(row + 0) * HD + e] = f2bf(r0);
    gatb[(row + 1) * HD + e] = f2bf(r1);
    gatb[(row + 2) * HD + e] = f2bf(r2);
    gatb[(row + 3) * HD + e] = f2bf(r3);
}
#undef EDGE_FMA8

// ---------------- Pass E: merge via bf16 MFMA + leakyrelu + residual --------
__global__ __launch_bounds__(256) void merge_mfma_kernel(
    const unsigned short* __restrict__ gatb,
    const float* __restrict__ merge_w, const float* __restrict__ merge_b,
    const float* __restrict__ x, float* __restrict__ out)
{
    int m0 = blockIdx.x * 128;
    int t = threadIdx.x, w = t >> 6, l = t & 63;

    __shared__ __align__(16) unsigned short As[128 * 128]; // 32 KB, swz
    __shared__ __align__(16) unsigned short Bs[64 * 128];  // 16 KB, swz

    #pragma unroll
    for (int rep = 0; rep < 8; ++rep) {
        int gid = t + 256 * rep;       // 0..2047
        int row = gid >> 4, gg = gid & 15;
        uint4 v = *(const uint4*)((const char*)gatb + ((size_t)(m0 + row)) * 256 + gg * 16);
        *(uint4*)((char*)As + row * 256 + ((gg ^ (row & 15)) << 4)) = v;
    }
    #pragma unroll
    for (int rep = 0; rep < 4; ++rep) {
        int gid = t + 256 * rep;       // 0..1023
        int col = gid >> 4, gg = gid & 15;
        float v[8];
        #pragma unroll
        for (int jj = 0; jj < 8; ++jj)
            v[jj] = merge_w[(gg * 8 + jj) * DD + col];
        uint4 pk = { pack2(v[0], v[1]), pack2(v[2], v[3]),
                     pack2(v[4], v[5]), pack2(v[6], v[7]) };
        *(uint4*)((char*)Bs + col * 256 + ((gg ^ (col & 15)) << 4)) = pk;
    }
    __syncthreads();

    int Mw = (w & 1) * 64, Nw = (w >> 1) * 32;
    int rsel = l & 15, ksel = l >> 4;

    f4v acc[4][2];
    #pragma unroll
    for (int mi = 0; mi < 4; ++mi)
        #pragma unroll
        for (int nf = 0; nf < 2; ++nf)
            acc[mi][nf] = (f4v){0.f, 0.f, 0.f, 0.f};

    s8v af[4][4], bfr[2][4];
    #pragma unroll
    for (int mi = 0; mi < 4; ++mi)
        #pragma unroll
        for (int ks = 0; ks < 4; ++ks) {
            int row = Mw + mi * 16 + rsel;
            int g2 = ks * 4 + ksel;
            af[mi][ks] = *(const s8v*)((const char*)As + row * 256 + ((g2 ^ (row & 15)) << 4));
        }
    #pragma unroll
    for (int nf = 0; nf < 2; ++nf)
        #pragma unroll
        for (int ks = 0; ks < 4; ++ks) {
            int col = Nw + nf * 16 + rsel;
            int g2 = ks * 4 + ksel;
            bfr[nf][ks] = *(const s8v*)((const char*)Bs + col * 256 + ((g2 ^ (col & 15)) << 4));
        }

    #pragma unroll
    for (int mi = 0; mi < 4; ++mi)
        #pragma unroll
        for (int nf = 0; nf < 2; ++nf)
            #pragma unroll
            for (int ks = 0; ks < 4; ++ks)
                acc[mi][nf] = __builtin_amdgcn_mfma_f32_16x16x32_bf16(
                    af[mi][ks], bfr[nf][ks], acc[mi][nf], 0, 0, 0);

    int i0 = (l >> 4) * 4;
    #pragma unroll
    for (int mi = 0; mi < 4; ++mi) {
        int m = m0 + Mw + mi * 16 + i0;          // 4 rows, same n/b (4 | 12 | 48)
        int n = m / BT, btb = m - n * BT;
        int b = btb / TT, t0 = btb - b * TT;
        #pragma unroll
        for (int nf = 0; nf < 2; ++nf) {
            int dd = Nw + nf * 16 + (l & 15);
            float mb = merge_b[dd];
            #pragma unroll
            for (int reg = 0; reg < 4; ++reg) {
                float mg = acc[mi][nf][reg] + mb;
                mg = mg > 0.f ? mg : mg * 0.01f;
                size_t oidx = (((size_t)b * NN + n) * TT + t0 + reg) * DD + dd;
                out[oidx] = mg + x[oidx];
            }
        }
    }
}

extern "C" void kernel_launch(void* const* d_in, const int* in_sizes, int n_in,
                              void* d_out, int out_size, void* d_ws, size_t ws_size,
                              hipStream_t stream)
{
    const float* x        = (const float*)d_in[0];
    const float* fc_w     = (const float*)d_in[1];
    const float* attn_l   = (const float*)d_in[2];
    const float* attn_r   = (const float*)d_in[3];
    const float* gat_bias = (const float*)d_in[4];
    const float* weight   = (const float*)d_in[5];
    const float* merge_w  = (const float*)d_in[6];
    const float* merge_b  = (const float*)d_in[7];
    const int*   src_idx  = (const int*)d_in[8];
    const int*   dst_idx  = (const int*)d_in[9];
    float*       out      = (float*)d_out;

    char* p = (char*)d_ws;
    auto carve = [&](size_t bytes) { char* r = p; p += (bytes + 15) & ~size_t(15); return r; };
    uint2* featp   = (uint2*)carve(sizeof(uint2) * (size_t)24 * NODES * 64);      // 37.8 MB
    float* alpha   = (float*)carve(sizeof(float) * (size_t)24 * CSR_CAP * 4);     // 24.8 MB
    unsigned short* gatb = (unsigned short*)carve(sizeof(unsigned short) * (size_t)NN * BT * HD); // 12.6 MB
    float* elp     = (float*)carve(sizeof(float) * (size_t)24 * NODES * 4);
    float* er      = (float*)carve(sizeof(float) * (size_t)KK * NN * BTH);
    float* alc     = (float*)carve(sizeof(float) * KK * HH * CC);
    float* arc     = (float*)carve(sizeof(float) * KK * HH * CC);
    int*   counts  = (int*)carve(sizeof(int) * KK * NN);
    int*   cursor  = (int*)carve(sizeof(int) * KK * NN);
    int4*  segs    = (int4*)carve(sizeof(int4) * NN);
    int*   csr_comb= (int*)carve(sizeof(int) * (CSR_CAP + 80));

    hipMemsetAsync(counts, 0, sizeof(int) * KK * NN, stream);

    aux_kernel<<<EDGE_BLOCKS + 1, 256, 0, stream>>>(
        dst_idx, counts, fc_w, attn_l, attn_r, alc, arc, featp, elp);

    feat_mfma_kernel<<<KK * NBLK, 256, 0, stream>>>(x, fc_w, featp);

    elr_kernel<<<NN, 128, 0, stream>>>(x, alc, arc, elp, er);

    scan_kernel<<<1, 1024, 0, stream>>>(counts, segs, cursor, csr_comb);
    scatter_kernel<<<EDGE_BLOCKS, 256, 0, stream>>>(src_idx, dst_idx, cursor, csr_comb);

    attn_kernel<<<1536, 256, 0, stream>>>(elp, er, segs, csr_comb, weight, alpha);

    agg_kernel<<<24 * 256, 256, 0, stream>>>(
        featp, alpha, segs, csr_comb, gat_bias, weight, gatb);

    merge_mfma_kernel<<<NN * BT / 128, 256, 0, stream>>>(gatb, merge_w, merge_b, x, out);
}